// Round 1
// baseline (824.727 us; speedup 1.0000x reference)
//
#include <hip/hip_runtime.h>
#include <math.h>

// ---- problem constants ----
constexpr int BB   = 1024;   // batch
constexpr int NN   = 2048;   // memory slots
constexpr int DD   = 64;     // memory width
constexpr int RR   = 4;      // read heads
constexpr int LSTM = 512;
constexpr int INP  = 256;
constexpr float GAMMA = 0.95f;

// ---- d_out flat layout (float elements, reference return order) ----
constexpr size_t OUT_OUT = 0;                                   // (B, 768)
constexpr size_t OUT_MT  = OUT_OUT + (size_t)BB * 768;          // (B, N, D)
constexpr size_t OUT_RT  = OUT_MT  + (size_t)BB * NN * DD;      // (B, 256)
constexpr size_t OUT_HT  = OUT_RT  + (size_t)BB * 256;          // (B, 512)
constexpr size_t OUT_CT  = OUT_HT  + (size_t)BB * 512;          // (B, 512)
constexpr size_t OUT_WU  = OUT_CT  + (size_t)BB * 512;          // (B, N)
constexpr size_t OUT_WR  = OUT_WU  + (size_t)BB * NN;           // (B, R*N)

// ---- scratch inside M_t region, per-batch slice of N*D = 131072 floats ----
// Header [0,264) is read by pass_b before it overwrites the slice.
constexpr int SLICE   = NN * DD;       // 131072
constexpr int OFF_A   = 0;             // a: 256
constexpr int OFF_SA  = 256;           // sigma(alpha): 4
constexpr int OFF_IDX = 260;           // idx4 (ints): 4
constexpr int OFF_IP  = 264;           // ip[n][r] float4: 8192
constexpr int OFF_MN  = OFF_IP + NN*4; // Mnorm: 2048       (=8456)
constexpr int OFF_G   = OFF_MN + NN;   // gates: 2048       (=10504)
constexpr int OFF_P   = OFF_G + 2048;  // p: 520            (=12552)
constexpr int OFF_K   = OFF_P + 520;   // k: 256            (=13072)
constexpr int OFF_KN  = OFF_K + 256;   // knorm: 4          (=13328)

__device__ __forceinline__ float sigmoidf_(float x) { return 1.0f / (1.0f + __expf(-x)); }

// ===================== GEMM 1: gates = [x,r_prev,h_prev] @ [W_ih|W_hh]^T + b =====================
__global__ __launch_bounds__(256) void gemm_gates(
    const float* __restrict__ x, const float* __restrict__ rprev, const float* __restrict__ hprev,
    const float* __restrict__ Wih, const float* __restrict__ Whh,
    const float* __restrict__ bih, const float* __restrict__ bhh,
    float* __restrict__ out)
{
    __shared__ float As[16][65];
    __shared__ float Bs[16][65];
    const int t = threadIdx.x;
    const int row0 = blockIdx.y * 64, col0 = blockIdx.x * 64;
    const int tx = t & 15, ty = t >> 4;
    float acc[4][4] = {};

    for (int k0 = 0; k0 < 1024; k0 += 16) {
        #pragma unroll
        for (int e = 0; e < 4; e++) {
            int el = t + e * 256;
            int i = el >> 4, kk = el & 15;
            int row = row0 + i, k = k0 + kk;
            float va;
            if (k < 256)      va = x[row * 256 + k];
            else if (k < 512) va = rprev[row * 256 + (k - 256)];
            else              va = hprev[row * 512 + (k - 512)];
            As[kk][i] = va;
            int j = col0 + i;
            float wv = (k < 512) ? Wih[j * 512 + k] : Whh[j * 512 + (k - 512)];
            Bs[kk][i] = wv;
        }
        __syncthreads();
        #pragma unroll
        for (int kk = 0; kk < 16; kk++) {
            float a4[4], b4[4];
            #pragma unroll
            for (int c = 0; c < 4; c++) { a4[c] = As[kk][ty * 4 + c]; b4[c] = Bs[kk][tx * 4 + c]; }
            #pragma unroll
            for (int ci = 0; ci < 4; ci++)
                #pragma unroll
                for (int cj = 0; cj < 4; cj++) acc[ci][cj] += a4[ci] * b4[cj];
        }
        __syncthreads();
    }
    float* mt = out + OUT_MT;
    #pragma unroll
    for (int ci = 0; ci < 4; ci++) {
        int row = row0 + ty * 4 + ci;
        #pragma unroll
        for (int cj = 0; cj < 4; cj++) {
            int col = col0 + tx * 4 + cj;
            mt[(size_t)row * SLICE + OFF_G + col] = acc[ci][cj] + bih[col] + bhh[col];
        }
    }
}

// ===================== LSTM pointwise =====================
__global__ __launch_bounds__(256) void lstm_pw(const float* __restrict__ cprev, float* __restrict__ out)
{
    const size_t idx = (size_t)blockIdx.x * 256 + threadIdx.x;  // 0 .. B*512-1
    const int b = (int)(idx >> 9), j = (int)(idx & 511);
    const float* g = out + OUT_MT + (size_t)b * SLICE + OFF_G;
    float ig = g[j], fg = g[512 + j], gg = g[1024 + j], og = g[1536 + j];
    float c = sigmoidf_(fg) * cprev[idx] + sigmoidf_(ig) * tanhf(gg);
    float h = sigmoidf_(og) * tanhf(c);
    out[OUT_CT + idx] = c;
    out[OUT_HT + idx] = h;
    out[(size_t)b * 768 + j] = h;
}

// ===================== GEMM 2: p = h_t @ W_lin^T + b_lin  (1024 x 516, K=512) =====================
__global__ __launch_bounds__(256) void gemm_p(
    const float* __restrict__ Wlin, const float* __restrict__ blin, float* __restrict__ out)
{
    __shared__ float As[16][65];
    __shared__ float Bs[16][65];
    const int t = threadIdx.x;
    const int row0 = blockIdx.y * 64, col0 = blockIdx.x * 64;
    const int tx = t & 15, ty = t >> 4;
    const float* ht = out + OUT_HT;
    float acc[4][4] = {};

    for (int k0 = 0; k0 < 512; k0 += 16) {
        #pragma unroll
        for (int e = 0; e < 4; e++) {
            int el = t + e * 256;
            int i = el >> 4, kk = el & 15;
            int row = row0 + i, k = k0 + kk;
            As[kk][i] = ht[(size_t)row * 512 + k];
            int j = col0 + i;
            Bs[kk][i] = (j < 516) ? Wlin[j * 512 + k] : 0.0f;
        }
        __syncthreads();
        #pragma unroll
        for (int kk = 0; kk < 16; kk++) {
            float a4[4], b4[4];
            #pragma unroll
            for (int c = 0; c < 4; c++) { a4[c] = As[kk][ty * 4 + c]; b4[c] = Bs[kk][tx * 4 + c]; }
            #pragma unroll
            for (int ci = 0; ci < 4; ci++)
                #pragma unroll
                for (int cj = 0; cj < 4; cj++) acc[ci][cj] += a4[ci] * b4[cj];
        }
        __syncthreads();
    }
    float* mt = out + OUT_MT;
    #pragma unroll
    for (int ci = 0; ci < 4; ci++) {
        int row = row0 + ty * 4 + ci;
        #pragma unroll
        for (int cj = 0; cj < 4; cj++) {
            int col = col0 + tx * 4 + cj;
            if (col < 516)
                mt[(size_t)row * SLICE + OFF_P + col] = acc[ci][cj] + blin[col];
        }
    }
}

// ===================== k, a, sigma_alpha, knorm =====================
__global__ __launch_bounds__(256) void kp_k(float* __restrict__ out)
{
    const int b = blockIdx.x, t = threadIdx.x;
    float* mt = out + OUT_MT;
    const size_t sl = (size_t)b * SLICE;
    const float* p = mt + sl + OFF_P;
    const int r = t >> 6, d = t & 63;
    float kv = tanhf(p[r * 64 + d]);
    float av = tanhf(p[256 + r * 64 + d]);
    mt[sl + OFF_K + r * 64 + d] = kv;
    mt[sl + OFF_A + r * 64 + d] = av;
    float s2 = kv * kv;
    #pragma unroll
    for (int off = 1; off < 64; off <<= 1) s2 += __shfl_xor(s2, off);
    if (d == 0) mt[sl + OFF_KN + r] = sqrtf(s2);
    if (t < 4) mt[sl + OFF_SA + t] = sigmoidf_(p[512 + t]);
}

// ===================== 4 smallest wu_prev indices (argsort(-wu) tail; tie -> larger index) =====================
__global__ __launch_bounds__(256) void argmin4_k(const float* __restrict__ wuprev, float* __restrict__ out)
{
    const int b = blockIdx.x, t = threadIdx.x;
    __shared__ float sval[256];
    __shared__ int   sidx[256];
    __shared__ int   chosen[4];
    float wu8[8];
    #pragma unroll
    for (int i = 0; i < 8; i++) wu8[i] = wuprev[(size_t)b * NN + t + i * 256];

    for (int it = 0; it < 4; it++) {
        float bv = 3.4e38f; int bi = -1;
        #pragma unroll
        for (int i = 0; i < 8; i++) {
            int n = t + i * 256;
            bool skip = false;
            for (int j = 0; j < it; j++) skip = skip || (n == chosen[j]);
            float v = wu8[i];
            if (!skip && (v < bv || (v == bv && n > bi))) { bv = v; bi = n; }
        }
        sval[t] = bv; sidx[t] = bi;
        __syncthreads();
        for (int s = 128; s; s >>= 1) {
            if (t < s) {
                float v2 = sval[t + s]; int i2 = sidx[t + s];
                if (v2 < sval[t] || (v2 == sval[t] && i2 > sidx[t])) { sval[t] = v2; sidx[t] = i2; }
            }
            __syncthreads();
        }
        if (t == 0) chosen[it] = sidx[0];
        __syncthreads();
    }
    if (t < 4)
        ((int*)(out + OUT_MT + (size_t)b * SLICE + OFF_IDX))[t] = chosen[t];
}

// ===================== Pass A: ip[b,r,n] = k . M_prev[b,n,:],  Mnorm[b,n] =====================
__global__ __launch_bounds__(256) void pass_a(const float* __restrict__ Mprev, float* __restrict__ out)
{
    const int b = blockIdx.y, chunk = blockIdx.x;
    const int t = threadIdx.x;
    const int wave = t >> 6, lane = t & 63;
    const int row4 = lane >> 4, d4 = lane & 15;
    float* mt = out + OUT_MT;
    const size_t sl = (size_t)b * SLICE;

    float4 k4[4];
    #pragma unroll
    for (int r = 0; r < 4; r++)
        k4[r] = *(const float4*)(mt + sl + OFF_K + r * 64 + d4 * 4);

    for (int it = 0; it < 8; it++) {
        int n = chunk * 128 + it * 16 + wave * 4 + row4;
        const float4 m4 = *(const float4*)(Mprev + ((size_t)b * NN + n) * DD + d4 * 4);
        float nrm = m4.x * m4.x + m4.y * m4.y + m4.z * m4.z + m4.w * m4.w;
        float ip0 = k4[0].x * m4.x + k4[0].y * m4.y + k4[0].z * m4.z + k4[0].w * m4.w;
        float ip1 = k4[1].x * m4.x + k4[1].y * m4.y + k4[1].z * m4.z + k4[1].w * m4.w;
        float ip2 = k4[2].x * m4.x + k4[2].y * m4.y + k4[2].z * m4.z + k4[2].w * m4.w;
        float ip3 = k4[3].x * m4.x + k4[3].y * m4.y + k4[3].z * m4.z + k4[3].w * m4.w;
        #pragma unroll
        for (int off = 1; off < 16; off <<= 1) {
            nrm += __shfl_xor(nrm, off);
            ip0 += __shfl_xor(ip0, off);
            ip1 += __shfl_xor(ip1, off);
            ip2 += __shfl_xor(ip2, off);
            ip3 += __shfl_xor(ip3, off);
        }
        if (d4 == 0) {
            *(float4*)(mt + sl + OFF_IP + (size_t)n * 4) = make_float4(ip0, ip1, ip2, ip3);
            mt[sl + OFF_MN + n] = sqrtf(nrm);
        }
    }
}

// ===================== softmax over n per (b,r) -> wr_t; wu_t =====================
__global__ __launch_bounds__(256) void softmax_k(
    const float* __restrict__ wuprev, const float* __restrict__ wrprev, float* __restrict__ out)
{
    const int b = blockIdx.x, t = threadIdx.x;
    float* mt = out + OUT_MT;
    const size_t sl = (size_t)b * SLICE;
    __shared__ float red[256];

    float kn[4], sa[4]; int id4[4];
    #pragma unroll
    for (int r = 0; r < 4; r++) { kn[r] = mt[sl + OFF_KN + r]; sa[r] = mt[sl + OFF_SA + r]; }
    const int* idxp = (const int*)(mt + sl + OFF_IDX);
    #pragma unroll
    for (int j = 0; j < 4; j++) id4[j] = idxp[j];

    float mn[8], wu[8], wl[8], acc[8];
    float ipv[4][8], wrp[4][8];
    #pragma unroll
    for (int i = 0; i < 8; i++) {
        int n = t + i * 256;
        mn[i] = mt[sl + OFF_MN + n];
        float4 f4 = *(const float4*)(mt + sl + OFF_IP + (size_t)n * 4);
        ipv[0][i] = f4.x; ipv[1][i] = f4.y; ipv[2][i] = f4.z; ipv[3][i] = f4.w;
        wu[i] = wuprev[(size_t)b * NN + n];
        wl[i] = (n == id4[0] || n == id4[1] || n == id4[2] || n == id4[3]) ? 1.0f : 0.0f;
        acc[i] = 0.0f;
        #pragma unroll
        for (int r = 0; r < 4; r++) wrp[r][i] = wrprev[(size_t)b * (RR * NN) + r * NN + n];
    }

    for (int r = 0; r < 4; r++) {
        float s[8];
        float lm = -3.4e38f;
        #pragma unroll
        for (int i = 0; i < 8; i++) {
            s[i] = ipv[r][i] / (kn[r] * mn[i] + 1e-8f);
            lm = fmaxf(lm, s[i]);
        }
        __syncthreads();
        red[t] = lm; __syncthreads();
        for (int sz = 128; sz; sz >>= 1) { if (t < sz) red[t] = fmaxf(red[t], red[t + sz]); __syncthreads(); }
        float mx = red[0];
        __syncthreads();
        float ls = 0.0f;
        #pragma unroll
        for (int i = 0; i < 8; i++) { s[i] = __expf(s[i] - mx); ls += s[i]; }
        red[t] = ls; __syncthreads();
        for (int sz = 128; sz; sz >>= 1) { if (t < sz) red[t] += red[t + sz]; __syncthreads(); }
        float inv = 1.0f / red[0];
        #pragma unroll
        for (int i = 0; i < 8; i++) {
            float w = s[i] * inv;
            out[OUT_WR + (size_t)b * (RR * NN) + r * NN + t + i * 256] = w;
            acc[i] += w + sa[r] * wrp[r][i] + (1.0f - sa[r]) * wl[i];
        }
    }
    #pragma unroll
    for (int i = 0; i < 8; i++)
        out[OUT_WU + (size_t)b * NN + t + i * 256] = GAMMA * wu[i] + acc[i];
}

// ===================== Pass B: M_t = M_prev*erase + ww^T a ; r_t = wr . M_t =====================
__global__ __launch_bounds__(256) void pass_b(
    const float* __restrict__ Mprev, const float* __restrict__ wrprev, float* __restrict__ out)
{
    const int b = blockIdx.x, t = threadIdx.x;
    const int wave = t >> 6, lane = t & 63;
    float* mt = out + OUT_MT;
    const size_t sl = (size_t)b * SLICE;

    float a_r[4], sa[4]; int id4[4];
    #pragma unroll
    for (int r = 0; r < 4; r++) { a_r[r] = mt[sl + OFF_A + r * 64 + lane]; sa[r] = mt[sl + OFF_SA + r]; }
    const int* idxp = (const int*)(mt + sl + OFF_IDX);
    #pragma unroll
    for (int j = 0; j < 4; j++) id4[j] = idxp[j];
    __syncthreads();   // header fully read before any M_t row is overwritten

    const float* wrt = out + OUT_WR + (size_t)b * (RR * NN);
    const float* wrp = wrprev + (size_t)b * (RR * NN);
    const int kill = id4[0];
    float racc[4] = {0.f, 0.f, 0.f, 0.f};

    const int n0 = wave * 512;
    for (int n = n0; n < n0 + 512; n++) {
        float m = Mprev[((size_t)b * NN + n) * DD + lane];
        float wlu = (n == id4[0] || n == id4[1] || n == id4[2] || n == id4[3]) ? 1.0f : 0.0f;
        float mtv = (n == kill) ? 0.0f : m;
        #pragma unroll
        for (int r = 0; r < 4; r++) {
            float ww = sa[r] * wrp[r * NN + n] + (1.0f - sa[r]) * wlu;
            mtv += ww * a_r[r];
        }
        mt[sl + (size_t)n * DD + lane] = mtv;
        #pragma unroll
        for (int r = 0; r < 4; r++) racc[r] += wrt[r * NN + n] * mtv;
    }

    __shared__ float lred[4][4][64];
    #pragma unroll
    for (int r = 0; r < 4; r++) lred[wave][r][lane] = racc[r];
    __syncthreads();
    {
        int r = t >> 6, d = t & 63;
        float s = lred[0][r][d] + lred[1][r][d] + lred[2][r][d] + lred[3][r][d];
        out[OUT_RT + (size_t)b * 256 + r * 64 + d] = s;
        out[(size_t)b * 768 + 512 + r * 64 + d] = s;
    }
}

// ===================== host =====================
extern "C" void kernel_launch(void* const* d_in, const int* in_sizes, int n_in,
                              void* d_out, int out_size, void* d_ws, size_t ws_size,
                              hipStream_t stream)
{
    const float* x      = (const float*)d_in[0];
    const float* Mprev  = (const float*)d_in[1];
    const float* rprev  = (const float*)d_in[2];
    const float* hprev  = (const float*)d_in[3];
    const float* cprev  = (const float*)d_in[4];
    const float* wuprev = (const float*)d_in[5];
    const float* wrprev = (const float*)d_in[6];
    const float* Wih    = (const float*)d_in[7];
    const float* bih    = (const float*)d_in[8];
    const float* Whh    = (const float*)d_in[9];
    const float* bhh    = (const float*)d_in[10];
    const float* Wlin   = (const float*)d_in[11];
    const float* blin   = (const float*)d_in[12];
    float* out = (float*)d_out;

    gemm_gates<<<dim3(32, 16), 256, 0, stream>>>(x, rprev, hprev, Wih, Whh, bih, bhh, out);
    lstm_pw<<<2048, 256, 0, stream>>>(cprev, out);
    gemm_p<<<dim3(9, 16), 256, 0, stream>>>(Wlin, blin, out);
    kp_k<<<1024, 256, 0, stream>>>(out);
    argmin4_k<<<1024, 256, 0, stream>>>(wuprev, out);
    pass_a<<<dim3(16, 1024), 256, 0, stream>>>(Mprev, out);
    softmax_k<<<1024, 256, 0, stream>>>(wuprev, wrprev, out);
    pass_b<<<1024, 256, 0, stream>>>(Mprev, wrprev, out);
}

// Round 5
// 681.011 us; speedup vs baseline: 1.2110x; 1.2110x over previous
//
#include <hip/hip_runtime.h>
#include <math.h>

// ---- problem constants ----
constexpr int BB   = 1024;   // batch
constexpr int NN   = 2048;   // memory slots
constexpr int DD   = 64;     // memory width
constexpr int RR   = 4;      // read heads
constexpr float GAMMA = 0.95f;

// ---- d_out flat layout (float elements, reference return order) ----
constexpr size_t OUT_OUT = 0;                                   // (B, 768)
constexpr size_t OUT_MT  = OUT_OUT + (size_t)BB * 768;          // (B, N, D)
constexpr size_t OUT_RT  = OUT_MT  + (size_t)BB * NN * DD;      // (B, 256)
constexpr size_t OUT_HT  = OUT_RT  + (size_t)BB * 256;          // (B, 512)
constexpr size_t OUT_CT  = OUT_HT  + (size_t)BB * 512;          // (B, 512)
constexpr size_t OUT_WU  = OUT_CT  + (size_t)BB * 512;          // (B, N)
constexpr size_t OUT_WR  = OUT_WU  + (size_t)BB * NN;           // (B, R*N)

// ---- scratch inside M_t region, per-batch slice of N*D = 131072 floats ----
// Header [0,264) is read by pass_b before it overwrites the slice.
constexpr int SLICE   = NN * DD;       // 131072
constexpr int OFF_A   = 0;             // a: 256
constexpr int OFF_SA  = 256;           // sigma(alpha): 4
constexpr int OFF_IDX = 260;           // idx4 (ints): 4
constexpr int OFF_IP  = 264;           // ip[n][r] float4: 8192
constexpr int OFF_MN  = OFF_IP + NN*4; // Mnorm: 2048       (=8456)
constexpr int OFF_G   = OFF_MN + NN;   // gates: 2048       (=10504)
constexpr int OFF_P   = OFF_G + 2048;  // p: 520            (=12552)
constexpr int OFF_K   = OFF_P + 520;   // k: 256            (=13072)
constexpr int OFF_KN  = OFF_K + 256;   // knorm: 4          (=13328)

__device__ __forceinline__ float sigmoidf_(float x) { return 1.0f / (1.0f + __expf(-x)); }

// ===================== GEMM 1: gates = [x,r_prev,h_prev] @ [W_ih|W_hh]^T + b =====================
__global__ __launch_bounds__(256) void gemm_gates(
    const float* __restrict__ x, const float* __restrict__ rprev, const float* __restrict__ hprev,
    const float* __restrict__ Wih, const float* __restrict__ Whh,
    const float* __restrict__ bih, const float* __restrict__ bhh,
    float* __restrict__ out)
{
    __shared__ float As[16][65];
    __shared__ float Bs[16][65];
    const int t = threadIdx.x;
    const int row0 = blockIdx.y * 64, col0 = blockIdx.x * 64;
    const int tx = t & 15, ty = t >> 4;
    float acc[4][4] = {};

    for (int k0 = 0; k0 < 1024; k0 += 16) {
        #pragma unroll
        for (int e = 0; e < 4; e++) {
            int el = t + e * 256;
            int i = el >> 4, kk = el & 15;
            int row = row0 + i, k = k0 + kk;
            float va;
            if (k < 256)      va = x[row * 256 + k];
            else if (k < 512) va = rprev[row * 256 + (k - 256)];
            else              va = hprev[row * 512 + (k - 512)];
            As[kk][i] = va;
            int j = col0 + i;
            float wv = (k < 512) ? Wih[j * 512 + k] : Whh[j * 512 + (k - 512)];
            Bs[kk][i] = wv;
        }
        __syncthreads();
        #pragma unroll
        for (int kk = 0; kk < 16; kk++) {
            float a4[4], b4[4];
            #pragma unroll
            for (int c = 0; c < 4; c++) { a4[c] = As[kk][ty * 4 + c]; b4[c] = Bs[kk][tx * 4 + c]; }
            #pragma unroll
            for (int ci = 0; ci < 4; ci++)
                #pragma unroll
                for (int cj = 0; cj < 4; cj++) acc[ci][cj] += a4[ci] * b4[cj];
        }
        __syncthreads();
    }
    float* mt = out + OUT_MT;
    #pragma unroll
    for (int ci = 0; ci < 4; ci++) {
        int row = row0 + ty * 4 + ci;
        #pragma unroll
        for (int cj = 0; cj < 4; cj++) {
            int col = col0 + tx * 4 + cj;
            mt[(size_t)row * SLICE + OFF_G + col] = acc[ci][cj] + bih[col] + bhh[col];
        }
    }
}

// ===================== LSTM pointwise =====================
__global__ __launch_bounds__(256) void lstm_pw(const float* __restrict__ cprev, float* __restrict__ out)
{
    const size_t idx = (size_t)blockIdx.x * 256 + threadIdx.x;  // 0 .. B*512-1
    const int b = (int)(idx >> 9), j = (int)(idx & 511);
    const float* g = out + OUT_MT + (size_t)b * SLICE + OFF_G;
    float ig = g[j], fg = g[512 + j], gg = g[1024 + j], og = g[1536 + j];
    float c = sigmoidf_(fg) * cprev[idx] + sigmoidf_(ig) * tanhf(gg);
    float h = sigmoidf_(og) * tanhf(c);
    out[OUT_CT + idx] = c;
    out[OUT_HT + idx] = h;
    out[(size_t)b * 768 + j] = h;
}

// ===================== GEMM 2: p = h_t @ W_lin^T + b_lin  (1024 x 516, K=512) =====================
__global__ __launch_bounds__(256) void gemm_p(
    const float* __restrict__ Wlin, const float* __restrict__ blin, float* __restrict__ out)
{
    __shared__ float As[16][65];
    __shared__ float Bs[16][65];
    const int t = threadIdx.x;
    const int row0 = blockIdx.y * 64, col0 = blockIdx.x * 64;
    const int tx = t & 15, ty = t >> 4;
    const float* ht = out + OUT_HT;
    float acc[4][4] = {};

    for (int k0 = 0; k0 < 512; k0 += 16) {
        #pragma unroll
        for (int e = 0; e < 4; e++) {
            int el = t + e * 256;
            int i = el >> 4, kk = el & 15;
            int row = row0 + i, k = k0 + kk;
            As[kk][i] = ht[(size_t)row * 512 + k];
            int j = col0 + i;
            Bs[kk][i] = (j < 516) ? Wlin[j * 512 + k] : 0.0f;
        }
        __syncthreads();
        #pragma unroll
        for (int kk = 0; kk < 16; kk++) {
            float a4[4], b4[4];
            #pragma unroll
            for (int c = 0; c < 4; c++) { a4[c] = As[kk][ty * 4 + c]; b4[c] = Bs[kk][tx * 4 + c]; }
            #pragma unroll
            for (int ci = 0; ci < 4; ci++)
                #pragma unroll
                for (int cj = 0; cj < 4; cj++) acc[ci][cj] += a4[ci] * b4[cj];
        }
        __syncthreads();
    }
    float* mt = out + OUT_MT;
    #pragma unroll
    for (int ci = 0; ci < 4; ci++) {
        int row = row0 + ty * 4 + ci;
        #pragma unroll
        for (int cj = 0; cj < 4; cj++) {
            int col = col0 + tx * 4 + cj;
            if (col < 516)
                mt[(size_t)row * SLICE + OFF_P + col] = acc[ci][cj] + blin[col];
        }
    }
}

// ===================== k, a, sigma_alpha, knorm =====================
__global__ __launch_bounds__(256) void kp_k(float* __restrict__ out)
{
    const int b = blockIdx.x, t = threadIdx.x;
    float* mt = out + OUT_MT;
    const size_t sl = (size_t)b * SLICE;
    const float* p = mt + sl + OFF_P;
    const int r = t >> 6, d = t & 63;
    float kv = tanhf(p[r * 64 + d]);
    float av = tanhf(p[256 + r * 64 + d]);
    mt[sl + OFF_K + r * 64 + d] = kv;
    mt[sl + OFF_A + r * 64 + d] = av;
    float s2 = kv * kv;
    #pragma unroll
    for (int off = 1; off < 64; off <<= 1) s2 += __shfl_xor(s2, off);
    if (d == 0) mt[sl + OFF_KN + r] = sqrtf(s2);
    if (t < 4) mt[sl + OFF_SA + t] = sigmoidf_(p[512 + t]);
}

// ===================== 4 smallest wu_prev indices (argsort(-wu) tail; tie -> larger index) =====================
__global__ __launch_bounds__(256) void argmin4_k(const float* __restrict__ wuprev, float* __restrict__ out)
{
    const int b = blockIdx.x, t = threadIdx.x;
    __shared__ float sval[256];
    __shared__ int   sidx[256];
    __shared__ int   chosen[4];
    float wu8[8];
    #pragma unroll
    for (int i = 0; i < 8; i++) wu8[i] = wuprev[(size_t)b * NN + t + i * 256];

    for (int it = 0; it < 4; it++) {
        float bv = 3.4e38f; int bi = -1;
        #pragma unroll
        for (int i = 0; i < 8; i++) {
            int n = t + i * 256;
            bool skip = false;
            for (int j = 0; j < it; j++) skip = skip || (n == chosen[j]);
            float v = wu8[i];
            if (!skip && (v < bv || (v == bv && n > bi))) { bv = v; bi = n; }
        }
        sval[t] = bv; sidx[t] = bi;
        __syncthreads();
        for (int s = 128; s; s >>= 1) {
            if (t < s) {
                float v2 = sval[t + s]; int i2 = sidx[t + s];
                if (v2 < sval[t] || (v2 == sval[t] && i2 > sidx[t])) { sval[t] = v2; sidx[t] = i2; }
            }
            __syncthreads();
        }
        if (t == 0) chosen[it] = sidx[0];
        __syncthreads();
    }
    if (t < 4)
        ((int*)(out + OUT_MT + (size_t)b * SLICE + OFF_IDX))[t] = chosen[t];
}

// ===================== Pass A: ip[b,r,n] = k . M_prev[b,n,:],  Mnorm[b,n] =====================
// 512 threads = 8 waves; lane = row4*16 + d4; each 16-lane group owns one row (float4/lane).
__global__ __launch_bounds__(512) void pass_a(const float* __restrict__ Mprev, float* __restrict__ out)
{
    const int b = blockIdx.y, chunk = blockIdx.x;   // 4 chunks x 512 rows
    const int t = threadIdx.x;
    const int wave = t >> 6, lane = t & 63;
    const int row4 = lane >> 4, d4 = lane & 15;
    float* mt = out + OUT_MT;
    const size_t sl = (size_t)b * SLICE;

    float4 k4[4];
    #pragma unroll
    for (int r = 0; r < 4; r++)
        k4[r] = *(const float4*)(mt + sl + OFF_K + r * 64 + d4 * 4);

    #pragma unroll 2
    for (int it = 0; it < 16; it++) {
        int n = chunk * 512 + it * 32 + wave * 4 + row4;
        const float4 m4 = *(const float4*)(Mprev + ((size_t)b * NN + n) * DD + d4 * 4);
        float nrm = m4.x * m4.x + m4.y * m4.y + m4.z * m4.z + m4.w * m4.w;
        float ip0 = k4[0].x * m4.x + k4[0].y * m4.y + k4[0].z * m4.z + k4[0].w * m4.w;
        float ip1 = k4[1].x * m4.x + k4[1].y * m4.y + k4[1].z * m4.z + k4[1].w * m4.w;
        float ip2 = k4[2].x * m4.x + k4[2].y * m4.y + k4[2].z * m4.z + k4[2].w * m4.w;
        float ip3 = k4[3].x * m4.x + k4[3].y * m4.y + k4[3].z * m4.z + k4[3].w * m4.w;
        #pragma unroll
        for (int off = 1; off < 16; off <<= 1) {
            nrm += __shfl_xor(nrm, off);
            ip0 += __shfl_xor(ip0, off);
            ip1 += __shfl_xor(ip1, off);
            ip2 += __shfl_xor(ip2, off);
            ip3 += __shfl_xor(ip3, off);
        }
        if (d4 == 0) {
            *(float4*)(mt + sl + OFF_IP + (size_t)n * 4) = make_float4(ip0, ip1, ip2, ip3);
            mt[sl + OFF_MN + n] = sqrtf(nrm);
        }
    }
}

// ===================== softmax over n per (b,r) -> wr_t; wu_t =====================
__global__ __launch_bounds__(256) void softmax_k(
    const float* __restrict__ wuprev, const float* __restrict__ wrprev, float* __restrict__ out)
{
    const int b = blockIdx.x, t = threadIdx.x;
    float* mt = out + OUT_MT;
    const size_t sl = (size_t)b * SLICE;
    __shared__ float red[256];

    float kn[4], sa[4]; int id4[4];
    #pragma unroll
    for (int r = 0; r < 4; r++) { kn[r] = mt[sl + OFF_KN + r]; sa[r] = mt[sl + OFF_SA + r]; }
    const int* idxp = (const int*)(mt + sl + OFF_IDX);
    #pragma unroll
    for (int j = 0; j < 4; j++) id4[j] = idxp[j];

    float mn[8], wu[8], wl[8], acc[8];
    float ipv[4][8], wrp[4][8];
    #pragma unroll
    for (int i = 0; i < 8; i++) {
        int n = t + i * 256;
        mn[i] = mt[sl + OFF_MN + n];
        float4 f4 = *(const float4*)(mt + sl + OFF_IP + (size_t)n * 4);
        ipv[0][i] = f4.x; ipv[1][i] = f4.y; ipv[2][i] = f4.z; ipv[3][i] = f4.w;
        wu[i] = wuprev[(size_t)b * NN + n];
        wl[i] = (n == id4[0] || n == id4[1] || n == id4[2] || n == id4[3]) ? 1.0f : 0.0f;
        acc[i] = 0.0f;
        #pragma unroll
        for (int r = 0; r < 4; r++) wrp[r][i] = wrprev[(size_t)b * (RR * NN) + r * NN + n];
    }

    for (int r = 0; r < 4; r++) {
        float s[8];
        float lm = -3.4e38f;
        #pragma unroll
        for (int i = 0; i < 8; i++) {
            s[i] = ipv[r][i] / (kn[r] * mn[i] + 1e-8f);
            lm = fmaxf(lm, s[i]);
        }
        __syncthreads();
        red[t] = lm; __syncthreads();
        for (int sz = 128; sz; sz >>= 1) { if (t < sz) red[t] = fmaxf(red[t], red[t + sz]); __syncthreads(); }
        float mx = red[0];
        __syncthreads();
        float ls = 0.0f;
        #pragma unroll
        for (int i = 0; i < 8; i++) { s[i] = __expf(s[i] - mx); ls += s[i]; }
        red[t] = ls; __syncthreads();
        for (int sz = 128; sz; sz >>= 1) { if (t < sz) red[t] += red[t + sz]; __syncthreads(); }
        float inv = 1.0f / red[0];
        #pragma unroll
        for (int i = 0; i < 8; i++) {
            float w = s[i] * inv;
            out[OUT_WR + (size_t)b * (RR * NN) + r * NN + t + i * 256] = w;
            acc[i] += w + sa[r] * wrp[r][i] + (1.0f - sa[r]) * wl[i];
        }
    }
    #pragma unroll
    for (int i = 0; i < 8; i++)
        out[OUT_WU + (size_t)b * NN + t + i * 256] = GAMMA * wu[i] + acc[i];
}

// ===================== Pass B: M_t = M_prev*erase + ww^T a ; r_t = wr . M_t =====================
// 512 threads = 8 waves; lane = row4*16 + d4; float4 per lane; 32 rows/block/iter.
__global__ __launch_bounds__(512) void pass_b(
    const float* __restrict__ Mprev, const float* __restrict__ wrprev, float* __restrict__ out)
{
    const int b = blockIdx.x, t = threadIdx.x;
    const int wave = t >> 6, lane = t & 63;
    const int row4 = lane >> 4, d4 = lane & 15;
    float* mt = out + OUT_MT;
    const size_t sl = (size_t)b * SLICE;

    float4 a4[4]; float sa[4]; int id4[4];
    #pragma unroll
    for (int r = 0; r < 4; r++) {
        a4[r] = *(const float4*)(mt + sl + OFF_A + r * 64 + d4 * 4);
        sa[r] = mt[sl + OFF_SA + r];
    }
    const int* idxp = (const int*)(mt + sl + OFF_IDX);
    #pragma unroll
    for (int j = 0; j < 4; j++) id4[j] = idxp[j];
    __syncthreads();   // header fully read before any M_t row is overwritten

    const float* wrt = out + OUT_WR + (size_t)b * (RR * NN);
    const float* wrp = wrprev + (size_t)b * (RR * NN);
    const int kill = id4[0];
    float4 racc[4];
    #pragma unroll
    for (int r = 0; r < 4; r++) racc[r] = make_float4(0.f, 0.f, 0.f, 0.f);

    #pragma unroll 2
    for (int it = 0; it < 64; it++) {
        const int n = it * 32 + wave * 4 + row4;
        float4 m4 = *(const float4*)(Mprev + ((size_t)b * NN + n) * DD + d4 * 4);
        const float wlu = (n == id4[0] || n == id4[1] || n == id4[2] || n == id4[3]) ? 1.0f : 0.0f;
        if (n == kill) { m4.x = 0.f; m4.y = 0.f; m4.z = 0.f; m4.w = 0.f; }
        float4 mtv = m4;
        #pragma unroll
        for (int r = 0; r < 4; r++) {
            const float ww = sa[r] * wrp[r * NN + n] + (1.0f - sa[r]) * wlu;
            mtv.x += ww * a4[r].x; mtv.y += ww * a4[r].y;
            mtv.z += ww * a4[r].z; mtv.w += ww * a4[r].w;
        }
        *(float4*)(mt + sl + (size_t)n * DD + d4 * 4) = mtv;
        #pragma unroll
        for (int r = 0; r < 4; r++) {
            const float w = wrt[r * NN + n];
            racc[r].x += w * mtv.x; racc[r].y += w * mtv.y;
            racc[r].z += w * mtv.z; racc[r].w += w * mtv.w;
        }
    }

    // reduce racc across the 4 row-groups within the wave (lanes differ in bits 4,5)
    #pragma unroll
    for (int r = 0; r < 4; r++) {
        #pragma unroll
        for (int off = 16; off < 64; off <<= 1) {
            racc[r].x += __shfl_xor(racc[r].x, off);
            racc[r].y += __shfl_xor(racc[r].y, off);
            racc[r].z += __shfl_xor(racc[r].z, off);
            racc[r].w += __shfl_xor(racc[r].w, off);
        }
    }

    __shared__ float4 sred[8][4][16];
    if (row4 == 0) {
        #pragma unroll
        for (int r = 0; r < 4; r++) sred[wave][r][d4] = racc[r];
    }
    __syncthreads();
    if (t < 64) {
        const int r = t >> 4, dd = t & 15;
        float4 s = make_float4(0.f, 0.f, 0.f, 0.f);
        #pragma unroll
        for (int w = 0; w < 8; w++) {
            float4 v = sred[w][r][dd];
            s.x += v.x; s.y += v.y; s.z += v.z; s.w += v.w;
        }
        *(float4*)(out + OUT_RT + (size_t)b * 256 + r * 64 + dd * 4) = s;
        *(float4*)(out + (size_t)b * 768 + 512 + r * 64 + dd * 4) = s;
    }
}

// ===================== host =====================
extern "C" void kernel_launch(void* const* d_in, const int* in_sizes, int n_in,
                              void* d_out, int out_size, void* d_ws, size_t ws_size,
                              hipStream_t stream)
{
    const float* x      = (const float*)d_in[0];
    const float* Mprev  = (const float*)d_in[1];
    const float* rprev  = (const float*)d_in[2];
    const float* hprev  = (const float*)d_in[3];
    const float* cprev  = (const float*)d_in[4];
    const float* wuprev = (const float*)d_in[5];
    const float* wrprev = (const float*)d_in[6];
    const float* Wih    = (const float*)d_in[7];
    const float* bih    = (const float*)d_in[8];
    const float* Whh    = (const float*)d_in[9];
    const float* bhh    = (const float*)d_in[10];
    const float* Wlin   = (const float*)d_in[11];
    const float* blin   = (const float*)d_in[12];
    float* out = (float*)d_out;

    gemm_gates<<<dim3(32, 16), 256, 0, stream>>>(x, rprev, hprev, Wih, Whh, bih, bhh, out);
    lstm_pw<<<2048, 256, 0, stream>>>(cprev, out);
    gemm_p<<<dim3(9, 16), 256, 0, stream>>>(Wlin, blin, out);
    kp_k<<<1024, 256, 0, stream>>>(out);
    argmin4_k<<<1024, 256, 0, stream>>>(wuprev, out);
    pass_a<<<dim3(4, 1024), 512, 0, stream>>>(Mprev, out);
    softmax_k<<<1024, 256, 0, stream>>>(wuprev, wrprev, out);
    pass_b<<<1024, 512, 0, stream>>>(Mprev, wrprev, out);
}

// Round 7
// 592.187 us; speedup vs baseline: 1.3927x; 1.1500x over previous
//
#include <hip/hip_runtime.h>
#include <math.h>

// ---- problem constants ----
constexpr int BB   = 1024;   // batch
constexpr int NN   = 2048;   // memory slots
constexpr int DD   = 64;     // memory width
constexpr int RR   = 4;      // read heads
constexpr float GAMMA = 0.95f;

// ---- d_out flat layout (float elements, reference return order) ----
constexpr size_t OUT_OUT = 0;                                   // (B, 768)
constexpr size_t OUT_MT  = OUT_OUT + (size_t)BB * 768;          // (B, N, D)
constexpr size_t OUT_RT  = OUT_MT  + (size_t)BB * NN * DD;      // (B, 256)
constexpr size_t OUT_HT  = OUT_RT  + (size_t)BB * 256;          // (B, 512)
constexpr size_t OUT_CT  = OUT_HT  + (size_t)BB * 512;          // (B, 512)
constexpr size_t OUT_WU  = OUT_CT  + (size_t)BB * 512;          // (B, N)
constexpr size_t OUT_WR  = OUT_WU  + (size_t)BB * NN;           // (B, R*N)

// ---- scratch inside M_t region, per-batch slice (header read before overwrite) ----
constexpr int SLICE   = NN * DD;       // 131072
constexpr int OFF_A   = 0;             // a: 256 floats
constexpr int OFF_G   = 8456 + NN;     // gates: 2048   (kept clear of rows consumed early)
constexpr int OFF_P   = OFF_G + 2048;  // p: 520
constexpr int OFF_K   = OFF_P + 520;   // k: 256

// ---- d_ws per-batch stash: 32 floats ----
constexpr int WS_STRIDE = 32;
constexpr int WS_SA  = 0;   // sigma(alpha): 4
constexpr int WS_KN  = 4;   // knorm: 4
constexpr int WS_M   = 8;   // softmax max: 4
constexpr int WS_Z   = 12;  // softmax denom: 4
constexpr int WS_IDX = 16;  // idx4 (int bits): 4

__device__ __forceinline__ float sigmoidf_(float x) { return 1.0f / (1.0f + __expf(-x)); }

// ===================== GEMM 1: gates = [x,r_prev,h_prev] @ [W_ih|W_hh]^T + b =====================
__global__ __launch_bounds__(256) void gemm_gates(
    const float* __restrict__ x, const float* __restrict__ rprev, const float* __restrict__ hprev,
    const float* __restrict__ Wih, const float* __restrict__ Whh,
    const float* __restrict__ bih, const float* __restrict__ bhh,
    float* __restrict__ out)
{
    __shared__ float As[16][65];
    __shared__ float Bs[16][65];
    const int t = threadIdx.x;
    const int row0 = blockIdx.y * 64, col0 = blockIdx.x * 64;
    const int tx = t & 15, ty = t >> 4;
    float acc[4][4] = {};

    for (int k0 = 0; k0 < 1024; k0 += 16) {
        #pragma unroll
        for (int e = 0; e < 4; e++) {
            int el = t + e * 256;
            int i = el >> 4, kk = el & 15;
            int row = row0 + i, k = k0 + kk;
            float va;
            if (k < 256)      va = x[row * 256 + k];
            else if (k < 512) va = rprev[row * 256 + (k - 256)];
            else              va = hprev[row * 512 + (k - 512)];
            As[kk][i] = va;
            int j = col0 + i;
            float wv = (k < 512) ? Wih[j * 512 + k] : Whh[j * 512 + (k - 512)];
            Bs[kk][i] = wv;
        }
        __syncthreads();
        #pragma unroll
        for (int kk = 0; kk < 16; kk++) {
            float a4[4], b4[4];
            #pragma unroll
            for (int c = 0; c < 4; c++) { a4[c] = As[kk][ty * 4 + c]; b4[c] = Bs[kk][tx * 4 + c]; }
            #pragma unroll
            for (int ci = 0; ci < 4; ci++)
                #pragma unroll
                for (int cj = 0; cj < 4; cj++) acc[ci][cj] += a4[ci] * b4[cj];
        }
        __syncthreads();
    }
    float* mt = out + OUT_MT;
    #pragma unroll
    for (int ci = 0; ci < 4; ci++) {
        int row = row0 + ty * 4 + ci;
        #pragma unroll
        for (int cj = 0; cj < 4; cj++) {
            int col = col0 + tx * 4 + cj;
            mt[(size_t)row * SLICE + OFF_G + col] = acc[ci][cj] + bih[col] + bhh[col];
        }
    }
}

// ===================== LSTM pointwise =====================
__global__ __launch_bounds__(256) void lstm_pw(const float* __restrict__ cprev, float* __restrict__ out)
{
    const size_t idx = (size_t)blockIdx.x * 256 + threadIdx.x;  // 0 .. B*512-1
    const int b = (int)(idx >> 9), j = (int)(idx & 511);
    const float* g = out + OUT_MT + (size_t)b * SLICE + OFF_G;
    float ig = g[j], fg = g[512 + j], gg = g[1024 + j], og = g[1536 + j];
    float c = sigmoidf_(fg) * cprev[idx] + sigmoidf_(ig) * tanhf(gg);
    float h = sigmoidf_(og) * tanhf(c);
    out[OUT_CT + idx] = c;
    out[OUT_HT + idx] = h;
    out[(size_t)b * 768 + j] = h;
}

// ===================== GEMM 2: p = h_t @ W_lin^T + b_lin  (1024 x 516, K=512) =====================
__global__ __launch_bounds__(256) void gemm_p(
    const float* __restrict__ Wlin, const float* __restrict__ blin, float* __restrict__ out)
{
    __shared__ float As[16][65];
    __shared__ float Bs[16][65];
    const int t = threadIdx.x;
    const int row0 = blockIdx.y * 64, col0 = blockIdx.x * 64;
    const int tx = t & 15, ty = t >> 4;
    const float* ht = out + OUT_HT;
    float acc[4][4] = {};

    for (int k0 = 0; k0 < 512; k0 += 16) {
        #pragma unroll
        for (int e = 0; e < 4; e++) {
            int el = t + e * 256;
            int i = el >> 4, kk = el & 15;
            int row = row0 + i, k = k0 + kk;
            As[kk][i] = ht[(size_t)row * 512 + k];
            int j = col0 + i;
            Bs[kk][i] = (j < 516) ? Wlin[j * 512 + k] : 0.0f;
        }
        __syncthreads();
        #pragma unroll
        for (int kk = 0; kk < 16; kk++) {
            float a4[4], b4[4];
            #pragma unroll
            for (int c = 0; c < 4; c++) { a4[c] = As[kk][ty * 4 + c]; b4[c] = Bs[kk][tx * 4 + c]; }
            #pragma unroll
            for (int ci = 0; ci < 4; ci++)
                #pragma unroll
                for (int cj = 0; cj < 4; cj++) acc[ci][cj] += a4[ci] * b4[cj];
        }
        __syncthreads();
    }
    float* mt = out + OUT_MT;
    #pragma unroll
    for (int ci = 0; ci < 4; ci++) {
        int row = row0 + ty * 4 + ci;
        #pragma unroll
        for (int cj = 0; cj < 4; cj++) {
            int col = col0 + tx * 4 + cj;
            if (col < 516)
                mt[(size_t)row * SLICE + OFF_P + col] = acc[ci][cj] + blin[col];
        }
    }
}

// ===================== k, a, sigma_alpha, knorm =====================
__global__ __launch_bounds__(256) void kp_k(float* __restrict__ out, float* __restrict__ ws)
{
    const int b = blockIdx.x, t = threadIdx.x;
    float* mt = out + OUT_MT;
    const size_t sl = (size_t)b * SLICE;
    const float* p = mt + sl + OFF_P;
    const int r = t >> 6, d = t & 63;
    float kv = tanhf(p[r * 64 + d]);
    float av = tanhf(p[256 + r * 64 + d]);
    mt[sl + OFF_K + r * 64 + d] = kv;
    mt[sl + OFF_A + r * 64 + d] = av;
    float s2 = kv * kv;
    #pragma unroll
    for (int off = 1; off < 64; off <<= 1) s2 += __shfl_xor(s2, off);
    float* wsb = ws + (size_t)b * WS_STRIDE;
    if (d == 0) wsb[WS_KN + r] = sqrtf(s2);
    if (t < 4) wsb[WS_SA + t] = sigmoidf_(p[512 + t]);
}

// ===================== 4 smallest wu_prev indices (argsort(-wu) tail; tie -> larger index) =====================
__global__ __launch_bounds__(256) void argmin4_k(const float* __restrict__ wuprev, float* __restrict__ ws)
{
    const int b = blockIdx.x, t = threadIdx.x;
    __shared__ float sval[256];
    __shared__ int   sidx[256];
    __shared__ int   chosen[4];
    float wu8[8];
    #pragma unroll
    for (int i = 0; i < 8; i++) wu8[i] = wuprev[(size_t)b * NN + t + i * 256];

    for (int it = 0; it < 4; it++) {
        float bv = 3.4e38f; int bi = -1;
        #pragma unroll
        for (int i = 0; i < 8; i++) {
            int n = t + i * 256;
            bool skip = false;
            for (int j = 0; j < it; j++) skip = skip || (n == chosen[j]);
            float v = wu8[i];
            if (!skip && (v < bv || (v == bv && n > bi))) { bv = v; bi = n; }
        }
        sval[t] = bv; sidx[t] = bi;
        __syncthreads();
        for (int s = 128; s; s >>= 1) {
            if (t < s) {
                float v2 = sval[t + s]; int i2 = sidx[t + s];
                if (v2 < sval[t] || (v2 == sval[t] && i2 > sidx[t])) { sval[t] = v2; sidx[t] = i2; }
            }
            __syncthreads();
        }
        if (t == 0) chosen[it] = sidx[0];
        __syncthreads();
    }
    if (t < 4)
        ((int*)(ws + (size_t)b * WS_STRIDE))[WS_IDX + t] = chosen[t];
}

// ===================== FUSED memory pass =====================
// One block per batch (512 thr = 8 waves). Single read of M_prev, single write of M_t.
// Per row n: ip = k.M[n], mn = ||M[n]||  -> stashed to OUT_WR/OUT_WU (read-then-overwrite later);
// M_t[n] = erase*M[n] + ww^T a (written); online-softmax accumulation of r_t = wr_t . M_t.
__global__ __launch_bounds__(512) void fused_mem(
    const float* __restrict__ Mprev, const float* __restrict__ wrprev,
    float* __restrict__ out, float* __restrict__ ws)
{
    const int b = blockIdx.x, t = threadIdx.x;
    const int wave = t >> 6, lane = t & 63;
    const int row4 = lane >> 4, d4 = lane & 15;
    float* mt = out + OUT_MT;
    const size_t sl = (size_t)b * SLICE;
    float* wsb = ws + (size_t)b * WS_STRIDE;

    // ---- header loads (k, a from M_t slice header; sa, kn, idx from ws) ----
    float4 k4[4], a4[4]; float sa[4], kn[4]; int id4[4];
    #pragma unroll
    for (int r = 0; r < 4; r++) {
        k4[r] = *(const float4*)(mt + sl + OFF_K + r * 64 + d4 * 4);
        a4[r] = *(const float4*)(mt + sl + OFF_A + r * 64 + d4 * 4);
        sa[r] = wsb[WS_SA + r];
        kn[r] = wsb[WS_KN + r];
        id4[r] = ((const int*)wsb)[WS_IDX + r];
    }
    __syncthreads();   // header fully read before any M_t row is overwritten

    const float* wrp = wrprev + (size_t)b * (RR * NN);
    float* ipc = out + OUT_WR + (size_t)b * (RR * NN);   // ip stash [r][n]
    float* mnc = out + OUT_WU + (size_t)b * NN;          // mn stash [n]
    const int kill = id4[0];

    float4 racc[4];
    float mrun[4], zrun[4];
    #pragma unroll
    for (int r = 0; r < 4; r++) {
        racc[r] = make_float4(0.f, 0.f, 0.f, 0.f);
        mrun[r] = -3.4e38f; zrun[r] = 0.f;
    }

    for (int it = 0; it < 64; it++) {
        const int n = it * 32 + wave * 4 + row4;
        float4 m4 = *(const float4*)(Mprev + ((size_t)b * NN + n) * DD + d4 * 4);

        float nrm = m4.x * m4.x + m4.y * m4.y + m4.z * m4.z + m4.w * m4.w;
        float ip0 = k4[0].x * m4.x + k4[0].y * m4.y + k4[0].z * m4.z + k4[0].w * m4.w;
        float ip1 = k4[1].x * m4.x + k4[1].y * m4.y + k4[1].z * m4.z + k4[1].w * m4.w;
        float ip2 = k4[2].x * m4.x + k4[2].y * m4.y + k4[2].z * m4.z + k4[2].w * m4.w;
        float ip3 = k4[3].x * m4.x + k4[3].y * m4.y + k4[3].z * m4.z + k4[3].w * m4.w;
        #pragma unroll
        for (int off = 1; off < 16; off <<= 1) {
            nrm += __shfl_xor(nrm, off);
            ip0 += __shfl_xor(ip0, off);
            ip1 += __shfl_xor(ip1, off);
            ip2 += __shfl_xor(ip2, off);
            ip3 += __shfl_xor(ip3, off);
        }
        const float mnv = sqrtf(nrm);
        if (d4 == 0) {
            ipc[0 * NN + n] = ip0; ipc[1 * NN + n] = ip1;
            ipc[2 * NN + n] = ip2; ipc[3 * NN + n] = ip3;
            mnc[n] = mnv;
        }
        float s_r[4];
        s_r[0] = ip0 / (kn[0] * mnv + 1e-8f);
        s_r[1] = ip1 / (kn[1] * mnv + 1e-8f);
        s_r[2] = ip2 / (kn[2] * mnv + 1e-8f);
        s_r[3] = ip3 / (kn[3] * mnv + 1e-8f);

        // M_t row
        const float wlu = (n == id4[0] || n == id4[1] || n == id4[2] || n == id4[3]) ? 1.0f : 0.0f;
        if (n == kill) { m4.x = 0.f; m4.y = 0.f; m4.z = 0.f; m4.w = 0.f; }
        float4 mtv = m4;
        #pragma unroll
        for (int r = 0; r < 4; r++) {
            const float ww = sa[r] * wrp[r * NN + n] + (1.0f - sa[r]) * wlu;
            mtv.x += ww * a4[r].x; mtv.y += ww * a4[r].y;
            mtv.z += ww * a4[r].z; mtv.w += ww * a4[r].w;
        }
        *(float4*)(mt + sl + (size_t)n * DD + d4 * 4) = mtv;

        // online-softmax accumulation of r_t
        #pragma unroll
        for (int r = 0; r < 4; r++) {
            if (s_r[r] > mrun[r]) {
                const float sc = __expf(mrun[r] - s_r[r]);
                racc[r].x = racc[r].x * sc + mtv.x;
                racc[r].y = racc[r].y * sc + mtv.y;
                racc[r].z = racc[r].z * sc + mtv.z;
                racc[r].w = racc[r].w * sc + mtv.w;
                zrun[r] = zrun[r] * sc + 1.0f;
                mrun[r] = s_r[r];
            } else {
                const float e = __expf(s_r[r] - mrun[r]);
                racc[r].x += e * mtv.x; racc[r].y += e * mtv.y;
                racc[r].z += e * mtv.z; racc[r].w += e * mtv.w;
                zrun[r] += e;
            }
        }
    }

    // merge the 4 row-groups within the wave (lane bits 4,5)
    #pragma unroll
    for (int off = 16; off < 64; off <<= 1) {
        #pragma unroll
        for (int r = 0; r < 4; r++) {
            const float m_o = __shfl_xor(mrun[r], off);
            const float z_o = __shfl_xor(zrun[r], off);
            float4 r_o;
            r_o.x = __shfl_xor(racc[r].x, off);
            r_o.y = __shfl_xor(racc[r].y, off);
            r_o.z = __shfl_xor(racc[r].z, off);
            r_o.w = __shfl_xor(racc[r].w, off);
            const float M  = fmaxf(mrun[r], m_o);
            const float sA = __expf(mrun[r] - M), sB = __expf(m_o - M);
            racc[r].x = racc[r].x * sA + r_o.x * sB;
            racc[r].y = racc[r].y * sA + r_o.y * sB;
            racc[r].z = racc[r].z * sA + r_o.z * sB;
            racc[r].w = racc[r].w * sA + r_o.w * sB;
            zrun[r] = zrun[r] * sA + z_o * sB;
            mrun[r] = M;
        }
    }

    // merge across the 8 waves via LDS
    __shared__ float  lm[8][4], lz[8][4];
    __shared__ float4 lr[8][4][16];
    if (row4 == 0) {
        #pragma unroll
        for (int r = 0; r < 4; r++) {
            lr[wave][r][d4] = racc[r];
            if (d4 == 0) { lm[wave][r] = mrun[r]; lz[wave][r] = zrun[r]; }
        }
    }
    __syncthreads();
    if (t < 64) {
        const int r = t >> 4, dd = t & 15;
        float M = -3.4e38f;
        #pragma unroll
        for (int w = 0; w < 8; w++) M = fmaxf(M, lm[w][r]);
        float Z = 0.f; float4 acc = make_float4(0.f, 0.f, 0.f, 0.f);
        #pragma unroll
        for (int w = 0; w < 8; w++) {
            const float sw = __expf(lm[w][r] - M);
            Z += lz[w][r] * sw;
            const float4 v = lr[w][r][dd];
            acc.x += v.x * sw; acc.y += v.y * sw; acc.z += v.z * sw; acc.w += v.w * sw;
        }
        const float inv = 1.0f / Z;
        const float4 rt = make_float4(acc.x * inv, acc.y * inv, acc.z * inv, acc.w * inv);
        *(float4*)(out + OUT_RT + (size_t)b * 256 + r * 64 + dd * 4) = rt;
        *(float4*)(out + (size_t)b * 768 + 512 + r * 64 + dd * 4) = rt;
        if (dd == 0) { wsb[WS_M + r] = M; wsb[WS_Z + r] = Z; }
    }
}

// ===================== softmax finalize: wr_t, wu_t (pure streaming, no reductions) =====================
__global__ __launch_bounds__(256) void softmax_k(
    const float* __restrict__ wuprev, const float* __restrict__ wrprev,
    float* __restrict__ out, const float* __restrict__ ws)
{
    const int b = blockIdx.x, t = threadIdx.x;
    const float* wsb = ws + (size_t)b * WS_STRIDE;

    float sa[4], kn[4], mf[4], zi[4]; int id4[4];
    #pragma unroll
    for (int r = 0; r < 4; r++) {
        sa[r] = wsb[WS_SA + r];
        kn[r] = wsb[WS_KN + r];
        mf[r] = wsb[WS_M + r];
        zi[r] = 1.0f / wsb[WS_Z + r];
        id4[r] = ((const int*)wsb)[WS_IDX + r];
    }

    float* ipc = out + OUT_WR + (size_t)b * (RR * NN);   // holds ip, becomes wr_t
    float* wuo = out + OUT_WU + (size_t)b * NN;          // holds mn, becomes wu_t
    const float* wrp = wrprev + (size_t)b * (RR * NN);

    #pragma unroll
    for (int i = 0; i < 8; i++) {
        const int n = t + i * 256;
        const float mn = wuo[n];
        const float wu = wuprev[(size_t)b * NN + n];
        const float wl = (n == id4[0] || n == id4[1] || n == id4[2] || n == id4[3]) ? 1.0f : 0.0f;
        float acc = 0.f;
        #pragma unroll
        for (int r = 0; r < 4; r++) {
            const float ip = ipc[r * NN + n];
            const float s  = ip / (kn[r] * mn + 1e-8f);
            const float wv = __expf(s - mf[r]) * zi[r];
            ipc[r * NN + n] = wv;
            acc += wv + sa[r] * wrp[r * NN + n] + (1.0f - sa[r]) * wl;
        }
        wuo[n] = GAMMA * wu + acc;
    }
}

// ===================== host =====================
extern "C" void kernel_launch(void* const* d_in, const int* in_sizes, int n_in,
                              void* d_out, int out_size, void* d_ws, size_t ws_size,
                              hipStream_t stream)
{
    const float* x      = (const float*)d_in[0];
    const float* Mprev  = (const float*)d_in[1];
    const float* rprev  = (const float*)d_in[2];
    const float* hprev  = (const float*)d_in[3];
    const float* cprev  = (const float*)d_in[4];
    const float* wuprev = (const float*)d_in[5];
    const float* wrprev = (const float*)d_in[6];
    const float* Wih    = (const float*)d_in[7];
    const float* bih    = (const float*)d_in[8];
    const float* Whh    = (const float*)d_in[9];
    const float* bhh    = (const float*)d_in[10];
    const float* Wlin   = (const float*)d_in[11];
    const float* blin   = (const float*)d_in[12];
    float* out = (float*)d_out;
    float* ws  = (float*)d_ws;   // needs 1024*32*4 = 128 KB

    gemm_gates<<<dim3(32, 16), 256, 0, stream>>>(x, rprev, hprev, Wih, Whh, bih, bhh, out);
    lstm_pw<<<2048, 256, 0, stream>>>(cprev, out);
    gemm_p<<<dim3(9, 16), 256, 0, stream>>>(Wlin, blin, out);
    kp_k<<<1024, 256, 0, stream>>>(out, ws);
    argmin4_k<<<1024, 256, 0, stream>>>(wuprev, ws);
    fused_mem<<<1024, 512, 0, stream>>>(Mprev, wrprev, out, ws);
    softmax_k<<<1024, 256, 0, stream>>>(wuprev, wrprev, out, ws);
}

// Round 8
// 519.342 us; speedup vs baseline: 1.5880x; 1.1403x over previous
//
#include <hip/hip_runtime.h>
#include <math.h>

// ---- problem constants ----
constexpr int BB   = 1024;   // batch
constexpr int NN   = 2048;   // memory slots
constexpr int DD   = 64;     // memory width
constexpr int RR   = 4;      // read heads
constexpr float GAMMA = 0.95f;

// ---- d_out flat layout (float elements, reference return order) ----
constexpr size_t OUT_OUT = 0;                                   // (B, 768)
constexpr size_t OUT_MT  = OUT_OUT + (size_t)BB * 768;          // (B, N, D)
constexpr size_t OUT_RT  = OUT_MT  + (size_t)BB * NN * DD;      // (B, 256)
constexpr size_t OUT_HT  = OUT_RT  + (size_t)BB * 256;          // (B, 512)
constexpr size_t OUT_CT  = OUT_HT  + (size_t)BB * 512;          // (B, 512)
constexpr size_t OUT_WU  = OUT_CT  + (size_t)BB * 512;          // (B, N)
constexpr size_t OUT_WR  = OUT_WU  + (size_t)BB * NN;           // (B, R*N)

// ---- scratch inside M_t region, per-batch slice (header read before overwrite) ----
constexpr int SLICE   = NN * DD;       // 131072
constexpr int OFF_A   = 0;             // a: 256 floats
constexpr int OFF_G   = 8456 + NN;     // gates: 2048
constexpr int OFF_P   = OFF_G + 2048;  // p: 520
constexpr int OFF_K   = OFF_P + 520;   // k: 256

// ---- d_ws per-batch stash: 32 floats ----
constexpr int WS_STRIDE = 32;
constexpr int WS_SA  = 0;   // sigma(alpha): 4
constexpr int WS_KN  = 4;   // knorm: 4
constexpr int WS_IDX = 16;  // idx4 (int bits): 4

__device__ __forceinline__ float sigmoidf_(float x) { return 1.0f / (1.0f + __expf(-x)); }

// VALU-pipe cross-lane add within each 16-lane row: x + dpp(x).
// Stages: quad_perm xor1 (0xB1), quad_perm xor2 (0x4E), row_ror:4 (0x124), row_ror:8 (0x128).
template<int CTRL>
__device__ __forceinline__ float dpp_add(float x) {
    int y = __builtin_amdgcn_update_dpp(0, __float_as_int(x), CTRL, 0xF, 0xF, false);
    return x + __int_as_float(y);
}
template<int CTRL>
__device__ __forceinline__ void dpp_add5(float& a, float& b, float& c, float& d, float& e) {
    a = dpp_add<CTRL>(a); b = dpp_add<CTRL>(b); c = dpp_add<CTRL>(c);
    d = dpp_add<CTRL>(d); e = dpp_add<CTRL>(e);
}

// ===================== GEMM 1: gates = [x,r_prev,h_prev] @ [W_ih|W_hh]^T + b =====================
__global__ __launch_bounds__(256) void gemm_gates(
    const float* __restrict__ x, const float* __restrict__ rprev, const float* __restrict__ hprev,
    const float* __restrict__ Wih, const float* __restrict__ Whh,
    const float* __restrict__ bih, const float* __restrict__ bhh,
    float* __restrict__ out)
{
    __shared__ float As[16][65];
    __shared__ float Bs[16][65];
    const int t = threadIdx.x;
    const int row0 = blockIdx.y * 64, col0 = blockIdx.x * 64;
    const int tx = t & 15, ty = t >> 4;
    float acc[4][4] = {};

    for (int k0 = 0; k0 < 1024; k0 += 16) {
        #pragma unroll
        for (int e = 0; e < 4; e++) {
            int el = t + e * 256;
            int i = el >> 4, kk = el & 15;
            int row = row0 + i, k = k0 + kk;
            float va;
            if (k < 256)      va = x[row * 256 + k];
            else if (k < 512) va = rprev[row * 256 + (k - 256)];
            else              va = hprev[row * 512 + (k - 512)];
            As[kk][i] = va;
            int j = col0 + i;
            float wv = (k < 512) ? Wih[j * 512 + k] : Whh[j * 512 + (k - 512)];
            Bs[kk][i] = wv;
        }
        __syncthreads();
        #pragma unroll
        for (int kk = 0; kk < 16; kk++) {
            float a4[4], b4[4];
            #pragma unroll
            for (int c = 0; c < 4; c++) { a4[c] = As[kk][ty * 4 + c]; b4[c] = Bs[kk][tx * 4 + c]; }
            #pragma unroll
            for (int ci = 0; ci < 4; ci++)
                #pragma unroll
                for (int cj = 0; cj < 4; cj++) acc[ci][cj] += a4[ci] * b4[cj];
        }
        __syncthreads();
    }
    float* mt = out + OUT_MT;
    #pragma unroll
    for (int ci = 0; ci < 4; ci++) {
        int row = row0 + ty * 4 + ci;
        #pragma unroll
        for (int cj = 0; cj < 4; cj++) {
            int col = col0 + tx * 4 + cj;
            mt[(size_t)row * SLICE + OFF_G + col] = acc[ci][cj] + bih[col] + bhh[col];
        }
    }
}

// ===================== LSTM pointwise =====================
__global__ __launch_bounds__(256) void lstm_pw(const float* __restrict__ cprev, float* __restrict__ out)
{
    const size_t idx = (size_t)blockIdx.x * 256 + threadIdx.x;  // 0 .. B*512-1
    const int b = (int)(idx >> 9), j = (int)(idx & 511);
    const float* g = out + OUT_MT + (size_t)b * SLICE + OFF_G;
    float ig = g[j], fg = g[512 + j], gg = g[1024 + j], og = g[1536 + j];
    float c = sigmoidf_(fg) * cprev[idx] + sigmoidf_(ig) * tanhf(gg);
    float h = sigmoidf_(og) * tanhf(c);
    out[OUT_CT + idx] = c;
    out[OUT_HT + idx] = h;
    out[(size_t)b * 768 + j] = h;
}

// ===================== GEMM 2: p = h_t @ W_lin^T + b_lin  (1024 x 516, K=512) =====================
__global__ __launch_bounds__(256) void gemm_p(
    const float* __restrict__ Wlin, const float* __restrict__ blin, float* __restrict__ out)
{
    __shared__ float As[16][65];
    __shared__ float Bs[16][65];
    const int t = threadIdx.x;
    const int row0 = blockIdx.y * 64, col0 = blockIdx.x * 64;
    const int tx = t & 15, ty = t >> 4;
    const float* ht = out + OUT_HT;
    float acc[4][4] = {};

    for (int k0 = 0; k0 < 512; k0 += 16) {
        #pragma unroll
        for (int e = 0; e < 4; e++) {
            int el = t + e * 256;
            int i = el >> 4, kk = el & 15;
            int row = row0 + i, k = k0 + kk;
            As[kk][i] = ht[(size_t)row * 512 + k];
            int j = col0 + i;
            Bs[kk][i] = (j < 516) ? Wlin[j * 512 + k] : 0.0f;
        }
        __syncthreads();
        #pragma unroll
        for (int kk = 0; kk < 16; kk++) {
            float a4[4], b4[4];
            #pragma unroll
            for (int c = 0; c < 4; c++) { a4[c] = As[kk][ty * 4 + c]; b4[c] = Bs[kk][tx * 4 + c]; }
            #pragma unroll
            for (int ci = 0; ci < 4; ci++)
                #pragma unroll
                for (int cj = 0; cj < 4; cj++) acc[ci][cj] += a4[ci] * b4[cj];
        }
        __syncthreads();
    }
    float* mt = out + OUT_MT;
    #pragma unroll
    for (int ci = 0; ci < 4; ci++) {
        int row = row0 + ty * 4 + ci;
        #pragma unroll
        for (int cj = 0; cj < 4; cj++) {
            int col = col0 + tx * 4 + cj;
            if (col < 516)
                mt[(size_t)row * SLICE + OFF_P + col] = acc[ci][cj] + blin[col];
        }
    }
}

// ===================== k, a, sigma_alpha, knorm =====================
__global__ __launch_bounds__(256) void kp_k(float* __restrict__ out, float* __restrict__ ws)
{
    const int b = blockIdx.x, t = threadIdx.x;
    float* mt = out + OUT_MT;
    const size_t sl = (size_t)b * SLICE;
    const float* p = mt + sl + OFF_P;
    const int r = t >> 6, d = t & 63;
    float kv = tanhf(p[r * 64 + d]);
    float av = tanhf(p[256 + r * 64 + d]);
    mt[sl + OFF_K + r * 64 + d] = kv;
    mt[sl + OFF_A + r * 64 + d] = av;
    float s2 = kv * kv;
    #pragma unroll
    for (int off = 1; off < 64; off <<= 1) s2 += __shfl_xor(s2, off);
    float* wsb = ws + (size_t)b * WS_STRIDE;
    if (d == 0) wsb[WS_KN + r] = sqrtf(s2);
    if (t < 4) wsb[WS_SA + t] = sigmoidf_(p[512 + t]);
}

// ===================== 4 smallest wu_prev indices (argsort(-wu) tail; tie -> larger index) =====================
__global__ __launch_bounds__(256) void argmin4_k(const float* __restrict__ wuprev, float* __restrict__ ws)
{
    const int b = blockIdx.x, t = threadIdx.x;
    __shared__ float sval[256];
    __shared__ int   sidx[256];
    __shared__ int   chosen[4];
    float wu8[8];
    #pragma unroll
    for (int i = 0; i < 8; i++) wu8[i] = wuprev[(size_t)b * NN + t + i * 256];

    for (int it = 0; it < 4; it++) {
        float bv = 3.4e38f; int bi = -1;
        #pragma unroll
        for (int i = 0; i < 8; i++) {
            int n = t + i * 256;
            bool skip = false;
            for (int j = 0; j < it; j++) skip = skip || (n == chosen[j]);
            float v = wu8[i];
            if (!skip && (v < bv || (v == bv && n > bi))) { bv = v; bi = n; }
        }
        sval[t] = bv; sidx[t] = bi;
        __syncthreads();
        for (int s = 128; s; s >>= 1) {
            if (t < s) {
                float v2 = sval[t + s]; int i2 = sidx[t + s];
                if (v2 < sval[t] || (v2 == sval[t] && i2 > sidx[t])) { sval[t] = v2; sidx[t] = i2; }
            }
            __syncthreads();
        }
        if (t == 0) chosen[it] = sidx[0];
        __syncthreads();
    }
    if (t < 4)
        ((int*)(ws + (size_t)b * WS_STRIDE))[WS_IDX + t] = chosen[t];
}

// ===================== FUSED memory pass + softmax finalize =====================
// One block per batch (512 thr = 8 waves). Single M_prev read, single M_t write.
// Raw-sum softmax (scores are cosine sims in [-1,1] -> exp never overflows; no max tracking).
// e=exp(s) stashed to LDS; phase 2 in-kernel computes wr_t, wu_t. r_t accumulated online.
__global__ __launch_bounds__(512) void fused_mem(
    const float* __restrict__ Mprev, const float* __restrict__ wrprev,
    const float* __restrict__ wuprev,
    float* __restrict__ out, const float* __restrict__ ws)
{
    const int b = blockIdx.x, t = threadIdx.x;
    const int wave = t >> 6, lane = t & 63;
    const int row4 = lane >> 4, d4 = lane & 15;
    float* mt = out + OUT_MT;
    const size_t sl = (size_t)b * SLICE;
    const float* wsb = ws + (size_t)b * WS_STRIDE;

    __shared__ float4 s_e4[NN];     // 32 KB: e[n][r]; tail reused as lr in final merge
    __shared__ float  lz[8][4];     // per-wave partial Z

    // ---- header loads ----
    float4 k4[4], a4[4]; float sa[4], omsa[4], rck[4]; int id4[4];
    #pragma unroll
    for (int r = 0; r < 4; r++) {
        k4[r] = *(const float4*)(mt + sl + OFF_K + r * 64 + d4 * 4);
        a4[r] = *(const float4*)(mt + sl + OFF_A + r * 64 + d4 * 4);
        sa[r]   = wsb[WS_SA + r];
        omsa[r] = 1.0f - sa[r];
        rck[r]  = 1.0f / wsb[WS_KN + r];
        id4[r]  = ((const int*)wsb)[WS_IDX + r];
    }
    __syncthreads();   // header fully read before any M_t row is overwritten

    const float* wrp = wrprev + (size_t)b * (RR * NN);
    const int kill = id4[0];

    float4 racc[4];
    float zrun[4];
    #pragma unroll
    for (int r = 0; r < 4; r++) { racc[r] = make_float4(0.f, 0.f, 0.f, 0.f); zrun[r] = 0.f; }

    for (int it = 0; it < 64; it++) {
        const int n = it * 32 + wave * 4 + row4;
        float4 m4 = *(const float4*)(Mprev + ((size_t)b * NN + n) * DD + d4 * 4);

        float nrm = m4.x * m4.x + m4.y * m4.y + m4.z * m4.z + m4.w * m4.w;
        float ip0 = k4[0].x * m4.x + k4[0].y * m4.y + k4[0].z * m4.z + k4[0].w * m4.w;
        float ip1 = k4[1].x * m4.x + k4[1].y * m4.y + k4[1].z * m4.z + k4[1].w * m4.w;
        float ip2 = k4[2].x * m4.x + k4[2].y * m4.y + k4[2].z * m4.z + k4[2].w * m4.w;
        float ip3 = k4[3].x * m4.x + k4[3].y * m4.y + k4[3].z * m4.z + k4[3].w * m4.w;
        // 16-lane reduce+broadcast on the VALU pipe (no DS traffic)
        dpp_add5<0xB1>(nrm, ip0, ip1, ip2, ip3);   // quad_perm xor1
        dpp_add5<0x4E>(nrm, ip0, ip1, ip2, ip3);   // quad_perm xor2
        dpp_add5<0x124>(nrm, ip0, ip1, ip2, ip3);  // row_ror:4
        dpp_add5<0x128>(nrm, ip0, ip1, ip2, ip3);  // row_ror:8

        const float rsn = rsqrtf(fmaxf(nrm, 1e-30f));
        const float e0 = __expf(ip0 * rck[0] * rsn);
        const float e1 = __expf(ip1 * rck[1] * rsn);
        const float e2 = __expf(ip2 * rck[2] * rsn);
        const float e3 = __expf(ip3 * rck[3] * rsn);
        if (d4 == 0) s_e4[n] = make_float4(e0, e1, e2, e3);

        // M_t row
        const float wlu = (n == id4[0] || n == id4[1] || n == id4[2] || n == id4[3]) ? 1.0f : 0.0f;
        if (n == kill) { m4.x = 0.f; m4.y = 0.f; m4.z = 0.f; m4.w = 0.f; }
        float4 mtv = m4;
        #pragma unroll
        for (int r = 0; r < 4; r++) {
            const float ww = sa[r] * wrp[r * NN + n] + omsa[r] * wlu;
            mtv.x += ww * a4[r].x; mtv.y += ww * a4[r].y;
            mtv.z += ww * a4[r].z; mtv.w += ww * a4[r].w;
        }
        *(float4*)(mt + sl + (size_t)n * DD + d4 * 4) = mtv;

        // raw-softmax accumulation of r_t numerator + Z
        racc[0].x += e0 * mtv.x; racc[0].y += e0 * mtv.y; racc[0].z += e0 * mtv.z; racc[0].w += e0 * mtv.w;
        racc[1].x += e1 * mtv.x; racc[1].y += e1 * mtv.y; racc[1].z += e1 * mtv.z; racc[1].w += e1 * mtv.w;
        racc[2].x += e2 * mtv.x; racc[2].y += e2 * mtv.y; racc[2].z += e2 * mtv.z; racc[2].w += e2 * mtv.w;
        racc[3].x += e3 * mtv.x; racc[3].y += e3 * mtv.y; racc[3].z += e3 * mtv.z; racc[3].w += e3 * mtv.w;
        zrun[0] += e0; zrun[1] += e1; zrun[2] += e2; zrun[3] += e3;
    }

    // merge the 4 row-groups within the wave (lane bits 4,5) — plain sums
    #pragma unroll
    for (int off = 16; off < 64; off <<= 1) {
        #pragma unroll
        for (int r = 0; r < 4; r++) {
            zrun[r] += __shfl_xor(zrun[r], off);
            racc[r].x += __shfl_xor(racc[r].x, off);
            racc[r].y += __shfl_xor(racc[r].y, off);
            racc[r].z += __shfl_xor(racc[r].z, off);
            racc[r].w += __shfl_xor(racc[r].w, off);
        }
    }
    if (lane == 0) {
        #pragma unroll
        for (int r = 0; r < 4; r++) lz[wave][r] = zrun[r];
    }
    __syncthreads();   // s_e4 + lz now visible block-wide

    // block-wide Z and its reciprocal (computed redundantly by every thread; cheap)
    float zi[4];
    #pragma unroll
    for (int r = 0; r < 4; r++) {
        float Z = 0.f;
        #pragma unroll
        for (int w = 0; w < 8; w++) Z += lz[w][r];
        zi[r] = 1.0f / Z;
    }

    // ---- phase 2: wr_t and wu_t (streaming; e from LDS) ----
    {
        float* wro = out + OUT_WR + (size_t)b * (RR * NN);
        float* wuo = out + OUT_WU + (size_t)b * NN;
        #pragma unroll
        for (int i = 0; i < 4; i++) {
            const int n = i * 512 + t;
            const float4 e4 = s_e4[n];
            const float wl = (n == id4[0] || n == id4[1] || n == id4[2] || n == id4[3]) ? 1.0f : 0.0f;
            const float wv0 = e4.x * zi[0], wv1 = e4.y * zi[1], wv2 = e4.z * zi[2], wv3 = e4.w * zi[3];
            wro[0 * NN + n] = wv0; wro[1 * NN + n] = wv1;
            wro[2 * NN + n] = wv2; wro[3 * NN + n] = wv3;
            float acc = wv0 + wv1 + wv2 + wv3;
            acc += sa[0] * wrp[0 * NN + n] + omsa[0] * wl;
            acc += sa[1] * wrp[1 * NN + n] + omsa[1] * wl;
            acc += sa[2] * wrp[2 * NN + n] + omsa[2] * wl;
            acc += sa[3] * wrp[3 * NN + n] + omsa[3] * wl;
            wuo[n] = GAMMA * wuprev[(size_t)b * NN + n] + acc;
        }
    }
    __syncthreads();   // phase-2 reads of s_e4 done; safe to reuse as lr

    // ---- final r_t merge across the 8 waves (overlay lr into s_e4) ----
    float4* lr = s_e4;   // 8 waves * 4 heads * 16 cols = 512 float4
    if (row4 == 0) {
        #pragma unroll
        for (int r = 0; r < 4; r++) lr[wave * 64 + r * 16 + d4] = racc[r];
    }
    __syncthreads();
    if (t < 64) {
        const int r = t >> 4, dd = t & 15;
        float4 s = make_float4(0.f, 0.f, 0.f, 0.f);
        #pragma unroll
        for (int w = 0; w < 8; w++) {
            const float4 v = lr[w * 64 + r * 16 + dd];
            s.x += v.x; s.y += v.y; s.z += v.z; s.w += v.w;
        }
        const float inv = zi[r];
        const float4 rt = make_float4(s.x * inv, s.y * inv, s.z * inv, s.w * inv);
        *(float4*)(out + OUT_RT + (size_t)b * 256 + r * 64 + dd * 4) = rt;
        *(float4*)(out + (size_t)b * 768 + 512 + r * 64 + dd * 4) = rt;
    }
}

// ===================== host =====================
extern "C" void kernel_launch(void* const* d_in, const int* in_sizes, int n_in,
                              void* d_out, int out_size, void* d_ws, size_t ws_size,
                              hipStream_t stream)
{
    const float* x      = (const float*)d_in[0];
    const float* Mprev  = (const float*)d_in[1];
    const float* rprev  = (const float*)d_in[2];
    const float* hprev  = (const float*)d_in[3];
    const float* cprev  = (const float*)d_in[4];
    const float* wuprev = (const float*)d_in[5];
    const float* wrprev = (const float*)d_in[6];
    const float* Wih    = (const float*)d_in[7];
    const float* bih    = (const float*)d_in[8];
    const float* Whh    = (const float*)d_in[9];
    const float* bhh    = (const float*)d_in[10];
    const float* Wlin   = (const float*)d_in[11];
    const float* blin   = (const float*)d_in[12];
    float* out = (float*)d_out;
    float* ws  = (float*)d_ws;   // needs 1024*32*4 = 128 KB

    gemm_gates<<<dim3(32, 16), 256, 0, stream>>>(x, rprev, hprev, Wih, Whh, bih, bhh, out);
    lstm_pw<<<2048, 256, 0, stream>>>(cprev, out);
    gemm_p<<<dim3(9, 16), 256, 0, stream>>>(Wlin, blin, out);
    kp_k<<<1024, 256, 0, stream>>>(out, ws);
    argmin4_k<<<1024, 256, 0, stream>>>(wuprev, ws);
    fused_mem<<<1024, 512, 0, stream>>>(Mprev, wrprev, wuprev, out, ws);
}

// Round 9
// 430.084 us; speedup vs baseline: 1.9176x; 1.2075x over previous
//
#include <hip/hip_runtime.h>
#include <math.h>

// ---- problem constants ----
constexpr int BB   = 1024;   // batch
constexpr int NN   = 2048;   // memory slots
constexpr int DD   = 64;     // memory width
constexpr int RR   = 4;      // read heads
constexpr float GAMMA = 0.95f;

// ---- d_out flat layout (float elements, reference return order) ----
constexpr size_t OUT_OUT = 0;                                   // (B, 768)
constexpr size_t OUT_MT  = OUT_OUT + (size_t)BB * 768;          // (B, N, D)
constexpr size_t OUT_RT  = OUT_MT  + (size_t)BB * NN * DD;      // (B, 256)
constexpr size_t OUT_HT  = OUT_RT  + (size_t)BB * 256;          // (B, 512)
constexpr size_t OUT_CT  = OUT_HT  + (size_t)BB * 512;          // (B, 512)
constexpr size_t OUT_WU  = OUT_CT  + (size_t)BB * 512;          // (B, N)
constexpr size_t OUT_WR  = OUT_WU  + (size_t)BB * NN;           // (B, R*N)

// ---- scratch inside M_t region, per-batch slice (header read before overwrite) ----
constexpr int SLICE   = NN * DD;       // 131072
constexpr int OFF_A   = 0;             // a: 256 floats
constexpr int OFF_G   = 8456 + NN;     // gates: 2048
constexpr int OFF_P   = OFF_G + 2048;  // p: 520
constexpr int OFF_K   = OFF_P + 520;   // k: 256

// ---- d_ws per-batch stash: 32 floats ----
constexpr int WS_STRIDE = 32;
constexpr int WS_SA  = 0;   // sigma(alpha): 4
constexpr int WS_KN  = 4;   // knorm: 4
constexpr int WS_IDX = 16;  // idx4 (int bits): 4

__device__ __forceinline__ float sigmoidf_(float x) { return 1.0f / (1.0f + __expf(-x)); }

// VALU-pipe cross-lane add within each 16-lane row: x + dpp(x).
template<int CTRL>
__device__ __forceinline__ float dpp_add(float x) {
    int y = __builtin_amdgcn_update_dpp(0, __float_as_int(x), CTRL, 0xF, 0xF, false);
    return x + __int_as_float(y);
}
template<int CTRL>
__device__ __forceinline__ void dpp_add5(float& a, float& b, float& c, float& d, float& e) {
    a = dpp_add<CTRL>(a); b = dpp_add<CTRL>(b); c = dpp_add<CTRL>(c);
    d = dpp_add<CTRL>(d); e = dpp_add<CTRL>(e);
}

// ===================== GEMM 1: gates = [x,r_prev,h_prev] @ [W_ih|W_hh]^T + b =====================
// float4 staging + float4 LDS fragment reads; LDS rows padded to 68 floats (272 B: 16B-aligned,
// bank stride 4 -> <=2-way conflicts = free).
__global__ __launch_bounds__(256) void gemm_gates(
    const float* __restrict__ x, const float* __restrict__ rprev, const float* __restrict__ hprev,
    const float* __restrict__ Wih, const float* __restrict__ Whh,
    const float* __restrict__ bih, const float* __restrict__ bhh,
    float* __restrict__ out)
{
    __shared__ float As[16][68];
    __shared__ float Bs[16][68];
    const int t = threadIdx.x;
    const int row0 = blockIdx.y * 64, col0 = blockIdx.x * 64;
    const int tx = t & 15, ty = t >> 4;
    const int li = t >> 2;            // 0..63: tile row / col index for staging
    const int kq = (t & 3) * 4;       // 0,4,8,12: k-quad within 16-wide k-tile
    float acc[4][4] = {};

    for (int k0 = 0; k0 < 1024; k0 += 16) {
        const int k = k0 + kq;
        // A tile: rows row0+li, k..k+3
        {
            const int row = row0 + li;
            float4 av;
            if (k < 256)      av = *(const float4*)(x + row * 256 + k);
            else if (k < 512) av = *(const float4*)(rprev + row * 256 + (k - 256));
            else              av = *(const float4*)(hprev + row * 512 + (k - 512));
            As[kq + 0][li] = av.x; As[kq + 1][li] = av.y;
            As[kq + 2][li] = av.z; As[kq + 3][li] = av.w;
        }
        // B tile: W rows col0+li, k..k+3
        {
            const int j = col0 + li;
            const float4 bv = (k < 512) ? *(const float4*)(Wih + j * 512 + k)
                                        : *(const float4*)(Whh + j * 512 + (k - 512));
            Bs[kq + 0][li] = bv.x; Bs[kq + 1][li] = bv.y;
            Bs[kq + 2][li] = bv.z; Bs[kq + 3][li] = bv.w;
        }
        __syncthreads();
        #pragma unroll
        for (int kk = 0; kk < 16; kk++) {
            const float4 a4 = *(const float4*)&As[kk][ty * 4];
            const float4 b4 = *(const float4*)&Bs[kk][tx * 4];
            acc[0][0] += a4.x * b4.x; acc[0][1] += a4.x * b4.y; acc[0][2] += a4.x * b4.z; acc[0][3] += a4.x * b4.w;
            acc[1][0] += a4.y * b4.x; acc[1][1] += a4.y * b4.y; acc[1][2] += a4.y * b4.z; acc[1][3] += a4.y * b4.w;
            acc[2][0] += a4.z * b4.x; acc[2][1] += a4.z * b4.y; acc[2][2] += a4.z * b4.z; acc[2][3] += a4.z * b4.w;
            acc[3][0] += a4.w * b4.x; acc[3][1] += a4.w * b4.y; acc[3][2] += a4.w * b4.z; acc[3][3] += a4.w * b4.w;
        }
        __syncthreads();
    }
    float* mt = out + OUT_MT;
    #pragma unroll
    for (int ci = 0; ci < 4; ci++) {
        int row = row0 + ty * 4 + ci;
        #pragma unroll
        for (int cj = 0; cj < 4; cj++) {
            int col = col0 + tx * 4 + cj;
            mt[(size_t)row * SLICE + OFF_G + col] = acc[ci][cj] + bih[col] + bhh[col];
        }
    }
}

// ===================== LSTM pointwise =====================
__global__ __launch_bounds__(256) void lstm_pw(const float* __restrict__ cprev, float* __restrict__ out)
{
    const size_t idx = (size_t)blockIdx.x * 256 + threadIdx.x;  // 0 .. B*512-1
    const int b = (int)(idx >> 9), j = (int)(idx & 511);
    const float* g = out + OUT_MT + (size_t)b * SLICE + OFF_G;
    float ig = g[j], fg = g[512 + j], gg = g[1024 + j], og = g[1536 + j];
    float c = sigmoidf_(fg) * cprev[idx] + sigmoidf_(ig) * tanhf(gg);
    float h = sigmoidf_(og) * tanhf(c);
    out[OUT_CT + idx] = c;
    out[OUT_HT + idx] = h;
    out[(size_t)b * 768 + j] = h;
}

// ===================== GEMM 2: p = h_t @ W_lin^T + b_lin  (1024 x 516, K=512) =====================
__global__ __launch_bounds__(256) void gemm_p(
    const float* __restrict__ Wlin, const float* __restrict__ blin, float* __restrict__ out)
{
    __shared__ float As[16][68];
    __shared__ float Bs[16][68];
    const int t = threadIdx.x;
    const int row0 = blockIdx.y * 64, col0 = blockIdx.x * 64;
    const int tx = t & 15, ty = t >> 4;
    const int li = t >> 2;
    const int kq = (t & 3) * 4;
    const float* ht = out + OUT_HT;
    float acc[4][4] = {};

    for (int k0 = 0; k0 < 512; k0 += 16) {
        const int k = k0 + kq;
        {
            const int row = row0 + li;
            const float4 av = *(const float4*)(ht + (size_t)row * 512 + k);
            As[kq + 0][li] = av.x; As[kq + 1][li] = av.y;
            As[kq + 2][li] = av.z; As[kq + 3][li] = av.w;
        }
        {
            const int j = col0 + li;
            float4 bv = make_float4(0.f, 0.f, 0.f, 0.f);
            if (j < 516) bv = *(const float4*)(Wlin + j * 512 + k);
            Bs[kq + 0][li] = bv.x; Bs[kq + 1][li] = bv.y;
            Bs[kq + 2][li] = bv.z; Bs[kq + 3][li] = bv.w;
        }
        __syncthreads();
        #pragma unroll
        for (int kk = 0; kk < 16; kk++) {
            const float4 a4 = *(const float4*)&As[kk][ty * 4];
            const float4 b4 = *(const float4*)&Bs[kk][tx * 4];
            acc[0][0] += a4.x * b4.x; acc[0][1] += a4.x * b4.y; acc[0][2] += a4.x * b4.z; acc[0][3] += a4.x * b4.w;
            acc[1][0] += a4.y * b4.x; acc[1][1] += a4.y * b4.y; acc[1][2] += a4.y * b4.z; acc[1][3] += a4.y * b4.w;
            acc[2][0] += a4.z * b4.x; acc[2][1] += a4.z * b4.y; acc[2][2] += a4.z * b4.z; acc[2][3] += a4.z * b4.w;
            acc[3][0] += a4.w * b4.x; acc[3][1] += a4.w * b4.y; acc[3][2] += a4.w * b4.z; acc[3][3] += a4.w * b4.w;
        }
        __syncthreads();
    }
    float* mt = out + OUT_MT;
    #pragma unroll
    for (int ci = 0; ci < 4; ci++) {
        int row = row0 + ty * 4 + ci;
        #pragma unroll
        for (int cj = 0; cj < 4; cj++) {
            int col = col0 + tx * 4 + cj;
            if (col < 516)
                mt[(size_t)row * SLICE + OFF_P + col] = acc[ci][cj] + blin[col];
        }
    }
}

// ===================== k/a/sigma_alpha/knorm + argmin4, fused (independent jobs, same grid) ==========
__global__ __launch_bounds__(256) void kp_argmin_k(
    const float* __restrict__ wuprev, float* __restrict__ out, float* __restrict__ ws)
{
    const int b = blockIdx.x, t = threadIdx.x;
    float* mt = out + OUT_MT;
    const size_t sl = (size_t)b * SLICE;
    float* wsb = ws + (size_t)b * WS_STRIDE;

    // ---- part 1: k, a, sigma(alpha), ||k|| ----
    {
        const float* p = mt + sl + OFF_P;
        const int r = t >> 6, d = t & 63;
        float kv = tanhf(p[r * 64 + d]);
        float av = tanhf(p[256 + r * 64 + d]);
        mt[sl + OFF_K + r * 64 + d] = kv;
        mt[sl + OFF_A + r * 64 + d] = av;
        float s2 = kv * kv;
        #pragma unroll
        for (int off = 1; off < 64; off <<= 1) s2 += __shfl_xor(s2, off);
        if (d == 0) wsb[WS_KN + r] = sqrtf(s2);
        if (t < 4) wsb[WS_SA + t] = sigmoidf_(p[512 + t]);
    }

    // ---- part 2: 4 smallest wu_prev indices (tie -> larger index) ----
    __shared__ float sval[256];
    __shared__ int   sidx[256];
    __shared__ int   chosen[4];
    float wu8[8];
    #pragma unroll
    for (int i = 0; i < 8; i++) wu8[i] = wuprev[(size_t)b * NN + t + i * 256];

    for (int it = 0; it < 4; it++) {
        float bv = 3.4e38f; int bi = -1;
        #pragma unroll
        for (int i = 0; i < 8; i++) {
            int n = t + i * 256;
            bool skip = false;
            for (int j = 0; j < it; j++) skip = skip || (n == chosen[j]);
            float v = wu8[i];
            if (!skip && (v < bv || (v == bv && n > bi))) { bv = v; bi = n; }
        }
        sval[t] = bv; sidx[t] = bi;
        __syncthreads();
        for (int s = 128; s; s >>= 1) {
            if (t < s) {
                float v2 = sval[t + s]; int i2 = sidx[t + s];
                if (v2 < sval[t] || (v2 == sval[t] && i2 > sidx[t])) { sval[t] = v2; sidx[t] = i2; }
            }
            __syncthreads();
        }
        if (t == 0) chosen[it] = sidx[0];
        __syncthreads();
    }
    if (t < 4)
        ((int*)wsb)[WS_IDX + t] = chosen[t];
}

// ===================== FUSED memory pass + softmax finalize =====================
// One block per batch (512 thr = 8 waves). Single M_prev read, single M_t write.
// Raw-sum softmax (cosine sims in [-1,1] -> exp never overflows; no max tracking).
__global__ __launch_bounds__(512) void fused_mem(
    const float* __restrict__ Mprev, const float* __restrict__ wrprev,
    const float* __restrict__ wuprev,
    float* __restrict__ out, const float* __restrict__ ws)
{
    const int b = blockIdx.x, t = threadIdx.x;
    const int wave = t >> 6, lane = t & 63;
    const int row4 = lane >> 4, d4 = lane & 15;
    float* mt = out + OUT_MT;
    const size_t sl = (size_t)b * SLICE;
    const float* wsb = ws + (size_t)b * WS_STRIDE;

    __shared__ float4 s_e4[NN];     // 32 KB: e[n][r]; tail reused as lr in final merge
    __shared__ float  lz[8][4];     // per-wave partial Z

    // ---- header loads ----
    float4 k4[4], a4[4]; float sa[4], omsa[4], rck[4]; int id4[4];
    #pragma unroll
    for (int r = 0; r < 4; r++) {
        k4[r] = *(const float4*)(mt + sl + OFF_K + r * 64 + d4 * 4);
        a4[r] = *(const float4*)(mt + sl + OFF_A + r * 64 + d4 * 4);
        sa[r]   = wsb[WS_SA + r];
        omsa[r] = 1.0f - sa[r];
        rck[r]  = 1.0f / wsb[WS_KN + r];
        id4[r]  = ((const int*)wsb)[WS_IDX + r];
    }
    __syncthreads();   // header fully read before any M_t row is overwritten

    const float* wrp = wrprev + (size_t)b * (RR * NN);
    const int kill = id4[0];

    float4 racc[4];
    float zrun[4];
    #pragma unroll
    for (int r = 0; r < 4; r++) { racc[r] = make_float4(0.f, 0.f, 0.f, 0.f); zrun[r] = 0.f; }

    for (int it = 0; it < 64; it++) {
        const int n = it * 32 + wave * 4 + row4;
        float4 m4 = *(const float4*)(Mprev + ((size_t)b * NN + n) * DD + d4 * 4);

        float nrm = m4.x * m4.x + m4.y * m4.y + m4.z * m4.z + m4.w * m4.w;
        float ip0 = k4[0].x * m4.x + k4[0].y * m4.y + k4[0].z * m4.z + k4[0].w * m4.w;
        float ip1 = k4[1].x * m4.x + k4[1].y * m4.y + k4[1].z * m4.z + k4[1].w * m4.w;
        float ip2 = k4[2].x * m4.x + k4[2].y * m4.y + k4[2].z * m4.z + k4[2].w * m4.w;
        float ip3 = k4[3].x * m4.x + k4[3].y * m4.y + k4[3].z * m4.z + k4[3].w * m4.w;
        // 16-lane reduce+broadcast on the VALU pipe (no DS traffic)
        dpp_add5<0xB1>(nrm, ip0, ip1, ip2, ip3);   // quad_perm xor1
        dpp_add5<0x4E>(nrm, ip0, ip1, ip2, ip3);   // quad_perm xor2
        dpp_add5<0x124>(nrm, ip0, ip1, ip2, ip3);  // row_ror:4
        dpp_add5<0x128>(nrm, ip0, ip1, ip2, ip3);  // row_ror:8

        const float rsn = rsqrtf(fmaxf(nrm, 1e-30f));
        const float e0 = __expf(ip0 * rck[0] * rsn);
        const float e1 = __expf(ip1 * rck[1] * rsn);
        const float e2 = __expf(ip2 * rck[2] * rsn);
        const float e3 = __expf(ip3 * rck[3] * rsn);
        if (d4 == 0) s_e4[n] = make_float4(e0, e1, e2, e3);

        // M_t row
        const float wlu = (n == id4[0] || n == id4[1] || n == id4[2] || n == id4[3]) ? 1.0f : 0.0f;
        if (n == kill) { m4.x = 0.f; m4.y = 0.f; m4.z = 0.f; m4.w = 0.f; }
        float4 mtv = m4;
        #pragma unroll
        for (int r = 0; r < 4; r++) {
            const float ww = sa[r] * wrp[r * NN + n] + omsa[r] * wlu;
            mtv.x += ww * a4[r].x; mtv.y += ww * a4[r].y;
            mtv.z += ww * a4[r].z; mtv.w += ww * a4[r].w;
        }
        *(float4*)(mt + sl + (size_t)n * DD + d4 * 4) = mtv;

        // raw-softmax accumulation of r_t numerator + Z
        racc[0].x += e0 * mtv.x; racc[0].y += e0 * mtv.y; racc[0].z += e0 * mtv.z; racc[0].w += e0 * mtv.w;
        racc[1].x += e1 * mtv.x; racc[1].y += e1 * mtv.y; racc[1].z += e1 * mtv.z; racc[1].w += e1 * mtv.w;
        racc[2].x += e2 * mtv.x; racc[2].y += e2 * mtv.y; racc[2].z += e2 * mtv.z; racc[2].w += e2 * mtv.w;
        racc[3].x += e3 * mtv.x; racc[3].y += e3 * mtv.y; racc[3].z += e3 * mtv.z; racc[3].w += e3 * mtv.w;
        zrun[0] += e0; zrun[1] += e1; zrun[2] += e2; zrun[3] += e3;
    }

    // merge the 4 row-groups within the wave (lane bits 4,5) — plain sums
    #pragma unroll
    for (int off = 16; off < 64; off <<= 1) {
        #pragma unroll
        for (int r = 0; r < 4; r++) {
            zrun[r] += __shfl_xor(zrun[r], off);
            racc[r].x += __shfl_xor(racc[r].x, off);
            racc[r].y += __shfl_xor(racc[r].y, off);
            racc[r].z += __shfl_xor(racc[r].z, off);
            racc[r].w += __shfl_xor(racc[r].w, off);
        }
    }
    if (lane == 0) {
        #pragma unroll
        for (int r = 0; r < 4; r++) lz[wave][r] = zrun[r];
    }
    __syncthreads();   // s_e4 + lz now visible block-wide

    // block-wide Z and its reciprocal
    float zi[4];
    #pragma unroll
    for (int r = 0; r < 4; r++) {
        float Z = 0.f;
        #pragma unroll
        for (int w = 0; w < 8; w++) Z += lz[w][r];
        zi[r] = 1.0f / Z;
    }

    // ---- phase 2: wr_t and wu_t (streaming; e from LDS) ----
    {
        float* wro = out + OUT_WR + (size_t)b * (RR * NN);
        float* wuo = out + OUT_WU + (size_t)b * NN;
        #pragma unroll
        for (int i = 0; i < 4; i++) {
            const int n = i * 512 + t;
            const float4 e4 = s_e4[n];
            const float wl = (n == id4[0] || n == id4[1] || n == id4[2] || n == id4[3]) ? 1.0f : 0.0f;
            const float wv0 = e4.x * zi[0], wv1 = e4.y * zi[1], wv2 = e4.z * zi[2], wv3 = e4.w * zi[3];
            wro[0 * NN + n] = wv0; wro[1 * NN + n] = wv1;
            wro[2 * NN + n] = wv2; wro[3 * NN + n] = wv3;
            float acc = wv0 + wv1 + wv2 + wv3;
            acc += sa[0] * wrp[0 * NN + n] + omsa[0] * wl;
            acc += sa[1] * wrp[1 * NN + n] + omsa[1] * wl;
            acc += sa[2] * wrp[2 * NN + n] + omsa[2] * wl;
            acc += sa[3] * wrp[3 * NN + n] + omsa[3] * wl;
            wuo[n] = GAMMA * wuprev[(size_t)b * NN + n] + acc;
        }
    }
    __syncthreads();   // phase-2 reads of s_e4 done; safe to reuse as lr

    // ---- final r_t merge across the 8 waves (overlay lr into s_e4) ----
    float4* lr = s_e4;   // 8 waves * 4 heads * 16 cols = 512 float4
    if (row4 == 0) {
        #pragma unroll
        for (int r = 0; r < 4; r++) lr[wave * 64 + r * 16 + d4] = racc[r];
    }
    __syncthreads();
    if (t < 64) {
        const int r = t >> 4, dd = t & 15;
        float4 s = make_float4(0.f, 0.f, 0.f, 0.f);
        #pragma unroll
        for (int w = 0; w < 8; w++) {
            const float4 v = lr[w * 64 + r * 16 + dd];
            s.x += v.x; s.y += v.y; s.z += v.z; s.w += v.w;
        }
        const float inv = zi[r];
        const float4 rt = make_float4(s.x * inv, s.y * inv, s.z * inv, s.w * inv);
        *(float4*)(out + OUT_RT + (size_t)b * 256 + r * 64 + dd * 4) = rt;
        *(float4*)(out + (size_t)b * 768 + 512 + r * 64 + dd * 4) = rt;
    }
}

// ===================== host =====================
extern "C" void kernel_launch(void* const* d_in, const int* in_sizes, int n_in,
                              void* d_out, int out_size, void* d_ws, size_t ws_size,
                              hipStream_t stream)
{
    const float* x      = (const float*)d_in[0];
    const float* Mprev  = (const float*)d_in[1];
    const float* rprev  = (const float*)d_in[2];
    const float* hprev  = (const float*)d_in[3];
    const float* cprev  = (const float*)d_in[4];
    const float* wuprev = (const float*)d_in[5];
    const float* wrprev = (const float*)d_in[6];
    const float* Wih    = (const float*)d_in[7];
    const float* bih    = (const float*)d_in[8];
    const float* Whh    = (const float*)d_in[9];
    const float* bhh    = (const float*)d_in[10];
    const float* Wlin   = (const float*)d_in[11];
    const float* blin   = (const float*)d_in[12];
    float* out = (float*)d_out;
    float* ws  = (float*)d_ws;   // needs 1024*32*4 = 128 KB

    gemm_gates<<<dim3(32, 16), 256, 0, stream>>>(x, rprev, hprev, Wih, Whh, bih, bhh, out);
    lstm_pw<<<2048, 256, 0, stream>>>(cprev, out);
    gemm_p<<<dim3(9, 16), 256, 0, stream>>>(Wlin, blin, out);
    kp_argmin_k<<<1024, 256, 0, stream>>>(wuprev, out, ws);
    fused_mem<<<1024, 512, 0, stream>>>(Mprev, wrprev, wuprev, out, ws);
}

// Round 10
// 386.662 us; speedup vs baseline: 2.1329x; 1.1123x over previous
//
#include <hip/hip_runtime.h>
#include <math.h>

// ---- problem constants ----
constexpr int BB   = 1024;   // batch
constexpr int NN   = 2048;   // memory slots
constexpr int DD   = 64;     // memory width
constexpr int RR   = 4;      // read heads
constexpr float GAMMA = 0.95f;

// ---- d_out flat layout (float elements, reference return order) ----
constexpr size_t OUT_OUT = 0;                                   // (B, 768)
constexpr size_t OUT_MT  = OUT_OUT + (size_t)BB * 768;          // (B, N, D)
constexpr size_t OUT_RT  = OUT_MT  + (size_t)BB * NN * DD;      // (B, 256)
constexpr size_t OUT_HT  = OUT_RT  + (size_t)BB * 256;          // (B, 512)
constexpr size_t OUT_CT  = OUT_HT  + (size_t)BB * 512;          // (B, 512)
constexpr size_t OUT_WU  = OUT_CT  + (size_t)BB * 512;          // (B, N)
constexpr size_t OUT_WR  = OUT_WU  + (size_t)BB * NN;           // (B, R*N)

// ---- scratch inside M_t region, per-batch slice (header read before overwrite) ----
constexpr int SLICE   = NN * DD;       // 131072
constexpr int OFF_A   = 0;             // a: 256 floats
constexpr int OFF_G   = 8456 + NN;     // gates: 2048
constexpr int OFF_P   = OFF_G + 2048;  // p: 520
constexpr int OFF_K   = OFF_P + 520;   // k: 256

// ---- d_ws per-batch stash: 32 floats ----
constexpr int WS_STRIDE = 32;
constexpr int WS_SA  = 0;   // sigma(alpha): 4
constexpr int WS_KN  = 4;   // knorm: 4
constexpr int WS_IDX = 16;  // idx4 (int bits): 4

__device__ __forceinline__ float sigmoidf_(float x) { return 1.0f / (1.0f + __expf(-x)); }

// VALU-pipe cross-lane add within each 16-lane row: x + dpp(x).
template<int CTRL>
__device__ __forceinline__ float dpp_add(float x) {
    int y = __builtin_amdgcn_update_dpp(0, __float_as_int(x), CTRL, 0xF, 0xF, false);
    return x + __int_as_float(y);
}
template<int CTRL>
__device__ __forceinline__ void dpp_add5(float& a, float& b, float& c, float& d, float& e) {
    a = dpp_add<CTRL>(a); b = dpp_add<CTRL>(b); c = dpp_add<CTRL>(c);
    d = dpp_add<CTRL>(d); e = dpp_add<CTRL>(e);
}

// ===================== GEMM 1: gates = [x,r_prev,h_prev] @ [W_ih|W_hh]^T + b =====================
__global__ __launch_bounds__(256) void gemm_gates(
    const float* __restrict__ x, const float* __restrict__ rprev, const float* __restrict__ hprev,
    const float* __restrict__ Wih, const float* __restrict__ Whh,
    const float* __restrict__ bih, const float* __restrict__ bhh,
    float* __restrict__ out)
{
    __shared__ float As[16][68];
    __shared__ float Bs[16][68];
    const int t = threadIdx.x;
    const int row0 = blockIdx.y * 64, col0 = blockIdx.x * 64;
    const int tx = t & 15, ty = t >> 4;
    const int li = t >> 2;            // 0..63: tile row / col index for staging
    const int kq = (t & 3) * 4;       // 0,4,8,12: k-quad within 16-wide k-tile
    float acc[4][4] = {};

    for (int k0 = 0; k0 < 1024; k0 += 16) {
        const int k = k0 + kq;
        {
            const int row = row0 + li;
            float4 av;
            if (k < 256)      av = *(const float4*)(x + row * 256 + k);
            else if (k < 512) av = *(const float4*)(rprev + row * 256 + (k - 256));
            else              av = *(const float4*)(hprev + row * 512 + (k - 512));
            As[kq + 0][li] = av.x; As[kq + 1][li] = av.y;
            As[kq + 2][li] = av.z; As[kq + 3][li] = av.w;
        }
        {
            const int j = col0 + li;
            const float4 bv = (k < 512) ? *(const float4*)(Wih + j * 512 + k)
                                        : *(const float4*)(Whh + j * 512 + (k - 512));
            Bs[kq + 0][li] = bv.x; Bs[kq + 1][li] = bv.y;
            Bs[kq + 2][li] = bv.z; Bs[kq + 3][li] = bv.w;
        }
        __syncthreads();
        #pragma unroll
        for (int kk = 0; kk < 16; kk++) {
            const float4 a4 = *(const float4*)&As[kk][ty * 4];
            const float4 b4 = *(const float4*)&Bs[kk][tx * 4];
            acc[0][0] += a4.x * b4.x; acc[0][1] += a4.x * b4.y; acc[0][2] += a4.x * b4.z; acc[0][3] += a4.x * b4.w;
            acc[1][0] += a4.y * b4.x; acc[1][1] += a4.y * b4.y; acc[1][2] += a4.y * b4.z; acc[1][3] += a4.y * b4.w;
            acc[2][0] += a4.z * b4.x; acc[2][1] += a4.z * b4.y; acc[2][2] += a4.z * b4.z; acc[2][3] += a4.z * b4.w;
            acc[3][0] += a4.w * b4.x; acc[3][1] += a4.w * b4.y; acc[3][2] += a4.w * b4.z; acc[3][3] += a4.w * b4.w;
        }
        __syncthreads();
    }
    float* mt = out + OUT_MT;
    #pragma unroll
    for (int ci = 0; ci < 4; ci++) {
        int row = row0 + ty * 4 + ci;
        #pragma unroll
        for (int cj = 0; cj < 4; cj++) {
            int col = col0 + tx * 4 + cj;
            mt[(size_t)row * SLICE + OFF_G + col] = acc[ci][cj] + bih[col] + bhh[col];
        }
    }
}

// ===================== LSTM pointwise =====================
__global__ __launch_bounds__(256) void lstm_pw(const float* __restrict__ cprev, float* __restrict__ out)
{
    const size_t idx = (size_t)blockIdx.x * 256 + threadIdx.x;  // 0 .. B*512-1
    const int b = (int)(idx >> 9), j = (int)(idx & 511);
    const float* g = out + OUT_MT + (size_t)b * SLICE + OFF_G;
    float ig = g[j], fg = g[512 + j], gg = g[1024 + j], og = g[1536 + j];
    float c = sigmoidf_(fg) * cprev[idx] + sigmoidf_(ig) * tanhf(gg);
    float h = sigmoidf_(og) * tanhf(c);
    out[OUT_CT + idx] = c;
    out[OUT_HT + idx] = h;
    out[(size_t)b * 768 + j] = h;
}

// ===================== GEMM 2: p = h_t @ W_lin^T + b_lin  (1024 x 516, K=512) =====================
__global__ __launch_bounds__(256) void gemm_p(
    const float* __restrict__ Wlin, const float* __restrict__ blin, float* __restrict__ out)
{
    __shared__ float As[16][68];
    __shared__ float Bs[16][68];
    const int t = threadIdx.x;
    const int row0 = blockIdx.y * 64, col0 = blockIdx.x * 64;
    const int tx = t & 15, ty = t >> 4;
    const int li = t >> 2;
    const int kq = (t & 3) * 4;
    const float* ht = out + OUT_HT;
    float acc[4][4] = {};

    for (int k0 = 0; k0 < 512; k0 += 16) {
        const int k = k0 + kq;
        {
            const int row = row0 + li;
            const float4 av = *(const float4*)(ht + (size_t)row * 512 + k);
            As[kq + 0][li] = av.x; As[kq + 1][li] = av.y;
            As[kq + 2][li] = av.z; As[kq + 3][li] = av.w;
        }
        {
            const int j = col0 + li;
            float4 bv = make_float4(0.f, 0.f, 0.f, 0.f);
            if (j < 516) bv = *(const float4*)(Wlin + j * 512 + k);
            Bs[kq + 0][li] = bv.x; Bs[kq + 1][li] = bv.y;
            Bs[kq + 2][li] = bv.z; Bs[kq + 3][li] = bv.w;
        }
        __syncthreads();
        #pragma unroll
        for (int kk = 0; kk < 16; kk++) {
            const float4 a4 = *(const float4*)&As[kk][ty * 4];
            const float4 b4 = *(const float4*)&Bs[kk][tx * 4];
            acc[0][0] += a4.x * b4.x; acc[0][1] += a4.x * b4.y; acc[0][2] += a4.x * b4.z; acc[0][3] += a4.x * b4.w;
            acc[1][0] += a4.y * b4.x; acc[1][1] += a4.y * b4.y; acc[1][2] += a4.y * b4.z; acc[1][3] += a4.y * b4.w;
            acc[2][0] += a4.z * b4.x; acc[2][1] += a4.z * b4.y; acc[2][2] += a4.z * b4.z; acc[2][3] += a4.z * b4.w;
            acc[3][0] += a4.w * b4.x; acc[3][1] += a4.w * b4.y; acc[3][2] += a4.w * b4.z; acc[3][3] += a4.w * b4.w;
        }
        __syncthreads();
    }
    float* mt = out + OUT_MT;
    #pragma unroll
    for (int ci = 0; ci < 4; ci++) {
        int row = row0 + ty * 4 + ci;
        #pragma unroll
        for (int cj = 0; cj < 4; cj++) {
            int col = col0 + tx * 4 + cj;
            if (col < 516)
                mt[(size_t)row * SLICE + OFF_P + col] = acc[ci][cj] + blin[col];
        }
    }
}

// ===================== k/a/sigma_alpha/knorm + argmin4, fused ==========
__global__ __launch_bounds__(256) void kp_argmin_k(
    const float* __restrict__ wuprev, float* __restrict__ out, float* __restrict__ ws)
{
    const int b = blockIdx.x, t = threadIdx.x;
    float* mt = out + OUT_MT;
    const size_t sl = (size_t)b * SLICE;
    float* wsb = ws + (size_t)b * WS_STRIDE;

    // ---- part 1: k, a, sigma(alpha), ||k|| ----
    {
        const float* p = mt + sl + OFF_P;
        const int r = t >> 6, d = t & 63;
        float kv = tanhf(p[r * 64 + d]);
        float av = tanhf(p[256 + r * 64 + d]);
        mt[sl + OFF_K + r * 64 + d] = kv;
        mt[sl + OFF_A + r * 64 + d] = av;
        float s2 = kv * kv;
        #pragma unroll
        for (int off = 1; off < 64; off <<= 1) s2 += __shfl_xor(s2, off);
        if (d == 0) wsb[WS_KN + r] = sqrtf(s2);
        if (t < 4) wsb[WS_SA + t] = sigmoidf_(p[512 + t]);
    }

    // ---- part 2: 4 smallest wu_prev indices (tie -> larger index) ----
    __shared__ float sval[256];
    __shared__ int   sidx[256];
    __shared__ int   chosen[4];
    float wu8[8];
    #pragma unroll
    for (int i = 0; i < 8; i++) wu8[i] = wuprev[(size_t)b * NN + t + i * 256];

    for (int it = 0; it < 4; it++) {
        float bv = 3.4e38f; int bi = -1;
        #pragma unroll
        for (int i = 0; i < 8; i++) {
            int n = t + i * 256;
            bool skip = false;
            for (int j = 0; j < it; j++) skip = skip || (n == chosen[j]);
            float v = wu8[i];
            if (!skip && (v < bv || (v == bv && n > bi))) { bv = v; bi = n; }
        }
        sval[t] = bv; sidx[t] = bi;
        __syncthreads();
        for (int s = 128; s; s >>= 1) {
            if (t < s) {
                float v2 = sval[t + s]; int i2 = sidx[t + s];
                if (v2 < sval[t] || (v2 == sval[t] && i2 > sidx[t])) { sval[t] = v2; sidx[t] = i2; }
            }
            __syncthreads();
        }
        if (t == 0) chosen[it] = sidx[0];
        __syncthreads();
    }
    if (t < 4)
        ((int*)wsb)[WS_IDX + t] = chosen[t];
}

// ===================== FUSED memory pass + softmax finalize =====================
// One block per batch (512 thr = 8 waves). Single M_prev read, single M_t write.
// Software-pipelined: next row's M load issued before current row's compute.
// Z is recomputed in phase 2 from the LDS e-buffer (no zrun in the hot loop).
__global__ __launch_bounds__(512) void fused_mem(
    const float* __restrict__ Mprev, const float* __restrict__ wrprev,
    const float* __restrict__ wuprev,
    float* __restrict__ out, const float* __restrict__ ws)
{
    const int b = blockIdx.x, t = threadIdx.x;
    const int wave = t >> 6, lane = t & 63;
    const int row4 = lane >> 4, d4 = lane & 15;
    float* mt = out + OUT_MT;
    const size_t sl = (size_t)b * SLICE;
    const float* wsb = ws + (size_t)b * WS_STRIDE;

    __shared__ float4 s_e4[NN];     // 32 KB: e[n][r]; reused as lr in final merge
    __shared__ float  lz[8][4];     // per-wave partial Z

    // ---- header loads (sa/rck/id4 are wave-uniform -> SGPRs) ----
    float4 k4[4], a4[4]; float sa[4], rck[4]; int id4[4];
    #pragma unroll
    for (int r = 0; r < 4; r++) {
        k4[r] = *(const float4*)(mt + sl + OFF_K + r * 64 + d4 * 4);
        a4[r] = *(const float4*)(mt + sl + OFF_A + r * 64 + d4 * 4);
        sa[r]  = wsb[WS_SA + r];
        rck[r] = 1.0f / wsb[WS_KN + r];
        id4[r] = ((const int*)wsb)[WS_IDX + r];
    }
    __syncthreads();   // header fully read before any M_t row is overwritten

    const float* wrp = wrprev + (size_t)b * (RR * NN);
    const int kill = id4[0];
    const size_t mbase = (size_t)b * NN * DD + (size_t)(d4 * 4);

    float4 racc[4];
    #pragma unroll
    for (int r = 0; r < 4; r++) racc[r] = make_float4(0.f, 0.f, 0.f, 0.f);

    // prologue: load first row
    float4 m4 = *(const float4*)(Mprev + mbase + (size_t)(wave * 4 + row4) * DD);

    for (int it = 0; it < 64; it++) {
        const int n = it * 32 + wave * 4 + row4;
        const int nn = (n + 32) & (NN - 1);            // wrapped prefetch index (last iter harmless)
        const float4 m4n = *(const float4*)(Mprev + mbase + (size_t)nn * DD);  // prefetch next
        const float w0 = wrp[0 * NN + n];
        const float w1 = wrp[1 * NN + n];
        const float w2 = wrp[2 * NN + n];
        const float w3 = wrp[3 * NN + n];

        float nrm = m4.x * m4.x + m4.y * m4.y + m4.z * m4.z + m4.w * m4.w;
        float ip0 = k4[0].x * m4.x + k4[0].y * m4.y + k4[0].z * m4.z + k4[0].w * m4.w;
        float ip1 = k4[1].x * m4.x + k4[1].y * m4.y + k4[1].z * m4.z + k4[1].w * m4.w;
        float ip2 = k4[2].x * m4.x + k4[2].y * m4.y + k4[2].z * m4.z + k4[2].w * m4.w;
        float ip3 = k4[3].x * m4.x + k4[3].y * m4.y + k4[3].z * m4.z + k4[3].w * m4.w;
        // 16-lane reduce+broadcast on the VALU pipe (no DS traffic)
        dpp_add5<0xB1>(nrm, ip0, ip1, ip2, ip3);   // quad_perm xor1
        dpp_add5<0x4E>(nrm, ip0, ip1, ip2, ip3);   // quad_perm xor2
        dpp_add5<0x124>(nrm, ip0, ip1, ip2, ip3);  // row_ror:4
        dpp_add5<0x128>(nrm, ip0, ip1, ip2, ip3);  // row_ror:8

        const float rsn = rsqrtf(fmaxf(nrm, 1e-30f));
        const float e0 = __expf(ip0 * rck[0] * rsn);
        const float e1 = __expf(ip1 * rck[1] * rsn);
        const float e2 = __expf(ip2 * rck[2] * rsn);
        const float e3 = __expf(ip3 * rck[3] * rsn);
        if (d4 == 0) s_e4[n] = make_float4(e0, e1, e2, e3);

        // M_t row:  ww = sa*wrp + (1-sa)*wlu  ==  fma(sa, wrp - wlu, wlu)
        const float wlu = (n == id4[0] || n == id4[1] || n == id4[2] || n == id4[3]) ? 1.0f : 0.0f;
        float4 mtv = m4;
        if (n == kill) { mtv.x = 0.f; mtv.y = 0.f; mtv.z = 0.f; mtv.w = 0.f; }
        const float ww0 = fmaf(sa[0], w0 - wlu, wlu);
        const float ww1 = fmaf(sa[1], w1 - wlu, wlu);
        const float ww2 = fmaf(sa[2], w2 - wlu, wlu);
        const float ww3 = fmaf(sa[3], w3 - wlu, wlu);
        mtv.x += ww0 * a4[0].x + ww1 * a4[1].x + ww2 * a4[2].x + ww3 * a4[3].x;
        mtv.y += ww0 * a4[0].y + ww1 * a4[1].y + ww2 * a4[2].y + ww3 * a4[3].y;
        mtv.z += ww0 * a4[0].z + ww1 * a4[1].z + ww2 * a4[2].z + ww3 * a4[3].z;
        mtv.w += ww0 * a4[0].w + ww1 * a4[1].w + ww2 * a4[2].w + ww3 * a4[3].w;
        *(float4*)(mt + sl + (size_t)n * DD + d4 * 4) = mtv;

        // raw-softmax accumulation of r_t numerator
        racc[0].x += e0 * mtv.x; racc[0].y += e0 * mtv.y; racc[0].z += e0 * mtv.z; racc[0].w += e0 * mtv.w;
        racc[1].x += e1 * mtv.x; racc[1].y += e1 * mtv.y; racc[1].z += e1 * mtv.z; racc[1].w += e1 * mtv.w;
        racc[2].x += e2 * mtv.x; racc[2].y += e2 * mtv.y; racc[2].z += e2 * mtv.z; racc[2].w += e2 * mtv.w;
        racc[3].x += e3 * mtv.x; racc[3].y += e3 * mtv.y; racc[3].z += e3 * mtv.z; racc[3].w += e3 * mtv.w;

        m4 = m4n;   // rotate pipeline
    }

    // merge racc across the 4 row-groups within the wave (lane bits 4,5)
    #pragma unroll
    for (int off = 16; off < 64; off <<= 1) {
        #pragma unroll
        for (int r = 0; r < 4; r++) {
            racc[r].x += __shfl_xor(racc[r].x, off);
            racc[r].y += __shfl_xor(racc[r].y, off);
            racc[r].z += __shfl_xor(racc[r].z, off);
            racc[r].w += __shfl_xor(racc[r].w, off);
        }
    }
    __syncthreads();   // s_e4 now visible block-wide

    // ---- Z from s_e4 (wave shuffle reduce + 8-wave LDS merge) ----
    float z0 = 0.f, z1 = 0.f, z2 = 0.f, z3 = 0.f;
    #pragma unroll
    for (int i = 0; i < 4; i++) {
        const float4 e4 = s_e4[i * 512 + t];
        z0 += e4.x; z1 += e4.y; z2 += e4.z; z3 += e4.w;
    }
    #pragma unroll
    for (int off = 1; off < 64; off <<= 1) {
        z0 += __shfl_xor(z0, off); z1 += __shfl_xor(z1, off);
        z2 += __shfl_xor(z2, off); z3 += __shfl_xor(z3, off);
    }
    if (lane == 0) { lz[wave][0] = z0; lz[wave][1] = z1; lz[wave][2] = z2; lz[wave][3] = z3; }
    __syncthreads();
    float zi[4];
    #pragma unroll
    for (int r = 0; r < 4; r++) {
        float Z = 0.f;
        #pragma unroll
        for (int w = 0; w < 8; w++) Z += lz[w][r];
        zi[r] = 1.0f / Z;
    }

    // ---- phase 2: wr_t and wu_t (streaming; e from LDS) ----
    {
        float* wro = out + OUT_WR + (size_t)b * (RR * NN);
        float* wuo = out + OUT_WU + (size_t)b * NN;
        #pragma unroll
        for (int i = 0; i < 4; i++) {
            const int n = i * 512 + t;
            const float4 e4 = s_e4[n];
            const float wl = (n == id4[0] || n == id4[1] || n == id4[2] || n == id4[3]) ? 1.0f : 0.0f;
            const float wv0 = e4.x * zi[0], wv1 = e4.y * zi[1], wv2 = e4.z * zi[2], wv3 = e4.w * zi[3];
            wro[0 * NN + n] = wv0; wro[1 * NN + n] = wv1;
            wro[2 * NN + n] = wv2; wro[3 * NN + n] = wv3;
            float acc = wv0 + wv1 + wv2 + wv3;
            acc += fmaf(sa[0], wrp[0 * NN + n] - wl, wl);
            acc += fmaf(sa[1], wrp[1 * NN + n] - wl, wl);
            acc += fmaf(sa[2], wrp[2 * NN + n] - wl, wl);
            acc += fmaf(sa[3], wrp[3 * NN + n] - wl, wl);
            wuo[n] = GAMMA * wuprev[(size_t)b * NN + n] + acc;
        }
    }
    __syncthreads();   // phase-2 reads of s_e4 done; safe to reuse as lr

    // ---- final r_t merge across the 8 waves (overlay lr into s_e4) ----
    float4* lr = s_e4;   // 8 waves * 4 heads * 16 cols = 512 float4
    if (row4 == 0) {
        #pragma unroll
        for (int r = 0; r < 4; r++) lr[wave * 64 + r * 16 + d4] = racc[r];
    }
    __syncthreads();
    if (t < 64) {
        const int r = t >> 4, dd = t & 15;
        float4 s = make_float4(0.f, 0.f, 0.f, 0.f);
        #pragma unroll
        for (int w = 0; w < 8; w++) {
            const float4 v = lr[w * 64 + r * 16 + dd];
            s.x += v.x; s.y += v.y; s.z += v.z; s.w += v.w;
        }
        const float inv = zi[r];
        const float4 rt = make_float4(s.x * inv, s.y * inv, s.z * inv, s.w * inv);
        *(float4*)(out + OUT_RT + (size_t)b * 256 + r * 64 + dd * 4) = rt;
        *(float4*)(out + (size_t)b * 768 + 512 + r * 64 + dd * 4) = rt;
    }
}

// ===================== host =====================
extern "C" void kernel_launch(void* const* d_in, const int* in_sizes, int n_in,
                              void* d_out, int out_size, void* d_ws, size_t ws_size,
                              hipStream_t stream)
{
    const float* x      = (const float*)d_in[0];
    const float* Mprev  = (const float*)d_in[1];
    const float* rprev  = (const float*)d_in[2];
    const float* hprev  = (const float*)d_in[3];
    const float* cprev  = (const float*)d_in[4];
    const float* wuprev = (const float*)d_in[5];
    const float* wrprev = (const float*)d_in[6];
    const float* Wih    = (const float*)d_in[7];
    const float* bih    = (const float*)d_in[8];
    const float* Whh    = (const float*)d_in[9];
    const float* bhh    = (const float*)d_in[10];
    const float* Wlin   = (const float*)d_in[11];
    const float* blin   = (const float*)d_in[12];
    float* out = (float*)d_out;
    float* ws  = (float*)d_ws;   // needs 1024*32*4 = 128 KB

    gemm_gates<<<dim3(32, 16), 256, 0, stream>>>(x, rprev, hprev, Wih, Whh, bih, bhh, out);
    lstm_pw<<<2048, 256, 0, stream>>>(cprev, out);
    gemm_p<<<dim3(9, 16), 256, 0, stream>>>(Wlin, blin, out);
    kp_argmin_k<<<1024, 256, 0, stream>>>(wuprev, out, ws);
    fused_mem<<<1024, 512, 0, stream>>>(Mprev, wrprev, wuprev, out, ws);
}